// Round 1
// baseline (8319.713 us; speedup 1.0000x reference)
//
#include <hip/hip_runtime.h>

#define B_    512
#define T_    48
#define FRAME_ 2048
#define PROJ_ 512
#define MID_  128
#define HID_  1024
#define G4_   4096

__device__ __forceinline__ float sigmoidf_(float x) {
    return 1.0f / (1.0f + expf(-x));
}

// ---------------------------------------------------------------------------
// embed: v[t][b][p] = video[b][t][:] . We[p][:] + be[p]
// grid (384, 8), block 256. Tiles: BM=64, BN=64, BK=32.
// ---------------------------------------------------------------------------
__global__ __launch_bounds__(256, 2)
void embed_kernel(const float* __restrict__ video, const float* __restrict__ We,
                  const float* __restrict__ be, float* __restrict__ v)
{
    __shared__ float Xs[32][68];
    __shared__ float Ws[32][68];
    const int m0  = blockIdx.x * 64;
    const int n0  = blockIdx.y * 64;
    const int tid = threadIdx.x;
    const int tx  = tid & 15, ty = tid >> 4;
    const int lr  = tid >> 3;
    const int c4  = (tid & 7) * 4;

    float acc[4][4] = {};

    for (int kt = 0; kt < FRAME_ / 32; ++kt) {
        const int k0 = kt * 32;
        __syncthreads();
#pragma unroll
        for (int rep = 0; rep < 2; ++rep) {
            const int r = lr + rep * 32;
            float4 xv = *(const float4*)&video[(size_t)(m0 + r) * FRAME_ + k0 + c4];
            Xs[c4 + 0][r] = xv.x; Xs[c4 + 1][r] = xv.y;
            Xs[c4 + 2][r] = xv.z; Xs[c4 + 3][r] = xv.w;
            float4 wv = *(const float4*)&We[(size_t)(n0 + r) * FRAME_ + k0 + c4];
            Ws[c4 + 0][r] = wv.x; Ws[c4 + 1][r] = wv.y;
            Ws[c4 + 2][r] = wv.z; Ws[c4 + 3][r] = wv.w;
        }
        __syncthreads();
#pragma unroll
        for (int k = 0; k < 32; ++k) {
            float4 av = *(const float4*)&Xs[k][ty * 4];
            float4 bv = *(const float4*)&Ws[k][tx * 4];
            const float a[4] = {av.x, av.y, av.z, av.w};
            const float b[4] = {bv.x, bv.y, bv.z, bv.w};
#pragma unroll
            for (int i = 0; i < 4; ++i)
#pragma unroll
                for (int j = 0; j < 4; ++j)
                    acc[i][j] = fmaf(a[i], b[j], acc[i][j]);
        }
    }

    const int nb = n0 + tx * 4;
    const float4 bev = *(const float4*)&be[nb];
#pragma unroll
    for (int i = 0; i < 4; ++i) {
        const int m = m0 + ty * 4 + i;
        const int t = m % T_;
        const int bb = m / T_;
        float4 o;
        o.x = acc[i][0] + bev.x; o.y = acc[i][1] + bev.y;
        o.z = acc[i][2] + bev.z; o.w = acc[i][3] + bev.w;
        *(float4*)&v[((size_t)t * B_ + bb) * PROJ_ + nb] = o;
    }
}

// ---------------------------------------------------------------------------
// boundary detector: keep[b] = (logit(b) > 0) ? 0 : 1   (keep = 1 - s)
// logit(b) = sum_i vs[i] * (vt[b]·Wsi[i] + h1[b]·Wsh[i] + bbd[i])
// grid 128, block 256; 4 batch rows per block; fp64 accumulation.
// ---------------------------------------------------------------------------
__global__ __launch_bounds__(256)
void bd_kernel(const float* __restrict__ vt, const float* __restrict__ h1i,
               const float* __restrict__ Wsi, const float* __restrict__ Wsh,
               const float* __restrict__ bbd, const float* __restrict__ vs,
               float* __restrict__ keep)
{
    __shared__ float xs[4][1536];
    __shared__ double red[4][128];
    const int tid = threadIdx.x;
    const int b0  = blockIdx.x * 4;

    for (int idx = tid; idx < 512; idx += 256) {
        const int r = idx >> 7, c = (idx & 127) << 2;
        *(float4*)&xs[r][c] = *(const float4*)&vt[(size_t)(b0 + r) * PROJ_ + c];
    }
    for (int idx = tid; idx < 1024; idx += 256) {
        const int r = idx >> 8, c = (idx & 255) << 2;
        *(float4*)&xs[r][512 + c] = *(const float4*)&h1i[(size_t)(b0 + r) * HID_ + c];
    }
    __syncthreads();

    const int mi = tid & 127;
    const int rg = tid >> 7;
    const int r0 = rg * 2, r1 = r0 + 1;

    double a0 = (double)bbd[mi], a1 = a0;

    const float4* wi4 = (const float4*)&Wsi[(size_t)mi * PROJ_];
    for (int k4 = 0; k4 < PROJ_ / 4; ++k4) {
        const float4 w = wi4[k4];
        const int k = k4 * 4;
        a0 += (double)w.x * xs[r0][k + 0] + (double)w.y * xs[r0][k + 1]
            + (double)w.z * xs[r0][k + 2] + (double)w.w * xs[r0][k + 3];
        a1 += (double)w.x * xs[r1][k + 0] + (double)w.y * xs[r1][k + 1]
            + (double)w.z * xs[r1][k + 2] + (double)w.w * xs[r1][k + 3];
    }
    const float4* wh4 = (const float4*)&Wsh[(size_t)mi * HID_];
    for (int k4 = 0; k4 < HID_ / 4; ++k4) {
        const float4 w = wh4[k4];
        const int k = 512 + k4 * 4;
        a0 += (double)w.x * xs[r0][k + 0] + (double)w.y * xs[r0][k + 1]
            + (double)w.z * xs[r0][k + 2] + (double)w.w * xs[r0][k + 3];
        a1 += (double)w.x * xs[r1][k + 0] + (double)w.y * xs[r1][k + 1]
            + (double)w.z * xs[r1][k + 2] + (double)w.w * xs[r1][k + 3];
    }
    const double vsm = (double)vs[mi];
    red[r0][mi] = vsm * a0;
    red[r1][mi] = vsm * a1;
    __syncthreads();

    if (tid < 4) {
        double s = 0.0;
        for (int i = 0; i < 128; ++i) s += red[tid][i];
        keep[b0 + tid] = (s > 0.0) ? 0.0f : 1.0f;
    }
}

// ---------------------------------------------------------------------------
// LSTM1 step: gates = vt @ W_ih^T + h1 @ W_hh^T ; fused activation/cell update.
// grid (8, 64): x = batch tile (64 rows), y = h tile (16 h-cols x 4 gates = 64 n-cols)
// block 256. BK=32, thread tile 4x4.
// ---------------------------------------------------------------------------
__global__ __launch_bounds__(256, 2)
void lstm_step_kernel(const float* __restrict__ vt, const float* __restrict__ h1i,
                      const float* __restrict__ W_ih, const float* __restrict__ W_hh,
                      const float* __restrict__ b1, const float* __restrict__ keep,
                      float* __restrict__ c1, float* __restrict__ h1o)
{
    __shared__ float smem[4352];               // 17 KB, reused by epilogue
    float (*Xs)[68] = (float(*)[68])smem;      // [32][68]
    float (*Ws)[68] = (float(*)[68])(smem + 2176);

    const int b0  = blockIdx.x * 64;
    const int h0  = blockIdx.y * 16;
    const int tid = threadIdx.x;
    const int tx  = tid & 15, ty = tid >> 4;
    const int lr  = tid >> 3;
    const int c4  = (tid & 7) * 4;

    float acc[4][4] = {};

    auto do_tile = [&](const float* __restrict__ X, int ldx,
                       const float* __restrict__ W, int k0) {
        __syncthreads();
#pragma unroll
        for (int rep = 0; rep < 2; ++rep) {
            const int r = lr + rep * 32;
            float4 xv = *(const float4*)&X[(size_t)(b0 + r) * ldx + k0 + c4];
            Xs[c4 + 0][r] = xv.x; Xs[c4 + 1][r] = xv.y;
            Xs[c4 + 2][r] = xv.z; Xs[c4 + 3][r] = xv.w;
            const int gate = r >> 4, hh = r & 15;
            float4 wv = *(const float4*)&W[(size_t)(gate * HID_ + h0 + hh) * ldx + k0 + c4];
            Ws[c4 + 0][r] = wv.x; Ws[c4 + 1][r] = wv.y;
            Ws[c4 + 2][r] = wv.z; Ws[c4 + 3][r] = wv.w;
        }
        __syncthreads();
#pragma unroll
        for (int k = 0; k < 32; ++k) {
            float4 av = *(const float4*)&Xs[k][ty * 4];
            float4 bv = *(const float4*)&Ws[k][tx * 4];
            const float a[4] = {av.x, av.y, av.z, av.w};
            const float b[4] = {bv.x, bv.y, bv.z, bv.w};
#pragma unroll
            for (int i = 0; i < 4; ++i)
#pragma unroll
                for (int j = 0; j < 4; ++j)
                    acc[i][j] = fmaf(a[i], b[j], acc[i][j]);
        }
    };

    for (int kt = 0; kt < PROJ_ / 32; ++kt) do_tile(vt,  PROJ_, W_ih, kt * 32);
    for (int kt = 0; kt < HID_  / 32; ++kt) do_tile(h1i, HID_,  W_hh, kt * 32);

    // epilogue: exchange accumulators so each thread owns all 4 gates of a (b,h)
    __syncthreads();
    float (*S)[68] = (float(*)[68])smem;       // [64][68]
#pragma unroll
    for (int i = 0; i < 4; ++i)
        *(float4*)&S[ty * 4 + i][tx * 4] =
            make_float4(acc[i][0], acc[i][1], acc[i][2], acc[i][3]);
    __syncthreads();

    const int h_l  = tid & 15;
    const int m4   = tid >> 4;                 // 0..15
    const int hidx = h0 + h_l;
    const float bI = b1[hidx];
    const float bF = b1[HID_ + hidx];
    const float bG = b1[2 * HID_ + hidx];
    const float bO = b1[3 * HID_ + hidx];

#pragma unroll
    for (int i = 0; i < 4; ++i) {
        const int m  = m4 * 4 + i;
        const int bb = b0 + m;
        const float gi = S[m][ 0 + h_l] + bI;
        const float gf = S[m][16 + h_l] + bF;
        const float gg = S[m][32 + h_l] + bG;
        const float go = S[m][48 + h_l] + bO;
        const float i_ = sigmoidf_(gi);
        const float f_ = sigmoidf_(gf);
        const float g_ = tanhf(gg);
        const float o_ = sigmoidf_(go);
        const size_t off = (size_t)bb * HID_ + hidx;
        const float cold = c1[off];
        float cn = f_ * cold + i_ * g_;
        float hn = o_ * tanhf(cn);
        const float kp = keep[bb];
        cn *= kp; hn *= kp;
        c1[off]  = cn;
        h1o[off] = hn;
    }
}

__global__ void b1sum_kernel(const float* __restrict__ bih,
                             const float* __restrict__ bhh,
                             float* __restrict__ b1)
{
    const int i = blockIdx.x * 256 + threadIdx.x;
    if (i < G4_) b1[i] = bih[i] + bhh[i];
}

// ---------------------------------------------------------------------------
extern "C" void kernel_launch(void* const* d_in, const int* in_sizes, int n_in,
                              void* d_out, int out_size, void* d_ws, size_t ws_size,
                              hipStream_t stream)
{
    const float* video = (const float*)d_in[0];
    const float* We    = (const float*)d_in[1];
    const float* be    = (const float*)d_in[2];
    const float* W1_ih = (const float*)d_in[3];
    const float* W1_hh = (const float*)d_in[4];
    const float* b1_ih = (const float*)d_in[5];
    const float* b1_hh = (const float*)d_in[6];
    // d_in[7], d_in[8] (W2_ih, W2_hh): dead — lstm2 never affects the output
    const float* Wsi   = (const float*)d_in[9];
    const float* Wsh   = (const float*)d_in[10];
    const float* bbd   = (const float*)d_in[11];
    const float* vs    = (const float*)d_in[12];
    float* out = (float*)d_out;

    float* ws   = (float*)d_ws;
    float* v    = ws;                                  // 48*512*512
    float* h1a  = v   + (size_t)T_ * B_ * PROJ_;       // 512*1024
    float* h1b  = h1a + (size_t)B_ * HID_;
    float* c1   = h1b + (size_t)B_ * HID_;
    float* keep = c1  + (size_t)B_ * HID_;             // 512
    float* b1   = keep + B_;                           // 4096

    hipMemsetAsync(h1a, 0, (size_t)B_ * HID_ * sizeof(float), stream);
    hipMemsetAsync(c1,  0, (size_t)B_ * HID_ * sizeof(float), stream);
    b1sum_kernel<<<16, 256, 0, stream>>>(b1_ih, b1_hh, b1);
    embed_kernel<<<dim3(384, 8), 256, 0, stream>>>(video, We, be, v);

    float* hin = h1a;
    float* hout = h1b;
    for (int t = 0; t < T_; ++t) {
        const float* vt = v + (size_t)t * B_ * PROJ_;
        bd_kernel<<<128, 256, 0, stream>>>(vt, hin, Wsi, Wsh, bbd, vs, keep);
        float* ho = (t == T_ - 1) ? out : hout;
        lstm_step_kernel<<<dim3(8, 64), 256, 0, stream>>>(vt, hin, W1_ih, W1_hh,
                                                          b1, keep, c1, ho);
        float* tmp = hin; hin = hout; hout = tmp;
    }
}

// Round 2
// 6050.743 us; speedup vs baseline: 1.3750x; 1.3750x over previous
//
#include <hip/hip_runtime.h>

#define B_     512
#define T_     48
#define FRAME_ 2048
#define PROJ_  512
#define MID_   128
#define HID_   1024
#define G4_    4096

typedef unsigned short u16;
typedef __bf16 bf16x8 __attribute__((ext_vector_type(8)));
typedef float  f32x4  __attribute__((ext_vector_type(4)));

__device__ __forceinline__ float sigmoidf_(float x) {
    return 1.0f / (1.0f + expf(-x));
}
__device__ __forceinline__ u16 f2bf_rn(float f) {
    unsigned int u = __float_as_uint(f);
    u += 0x7fffu + ((u >> 16) & 1u);
    return (u16)(u >> 16);
}
__device__ __forceinline__ float bf2f(u16 s) {
    return __uint_as_float(((unsigned int)s) << 16);
}
__device__ __forceinline__ void gld16(const void* g, void* l) {
    __builtin_amdgcn_global_load_lds((const __attribute__((address_space(1))) void*)g,
                                     (__attribute__((address_space(3))) void*)l, 16, 0, 0);
}

// ---------------------------------------------------------------------------
// embed: v[t][b][p] = video[b][t][:] . We[p][:] + be[p]  -> split bf16 hi/lo
// grid (384, 8), block 256. BM=64, BN=64, BK=32.
// ---------------------------------------------------------------------------
__global__ __launch_bounds__(256, 2)
void embed_kernel(const float* __restrict__ video, const float* __restrict__ We,
                  const float* __restrict__ be,
                  u16* __restrict__ vhi, u16* __restrict__ vlo)
{
    __shared__ float Xs[32][68];
    __shared__ float Ws[32][68];
    const int m0  = blockIdx.x * 64;
    const int n0  = blockIdx.y * 64;
    const int tid = threadIdx.x;
    const int tx  = tid & 15, ty = tid >> 4;
    const int lr  = tid >> 3;
    const int c4  = (tid & 7) * 4;

    float acc[4][4] = {};

    for (int kt = 0; kt < FRAME_ / 32; ++kt) {
        const int k0 = kt * 32;
        __syncthreads();
#pragma unroll
        for (int rep = 0; rep < 2; ++rep) {
            const int r = lr + rep * 32;
            float4 xv = *(const float4*)&video[(size_t)(m0 + r) * FRAME_ + k0 + c4];
            Xs[c4 + 0][r] = xv.x; Xs[c4 + 1][r] = xv.y;
            Xs[c4 + 2][r] = xv.z; Xs[c4 + 3][r] = xv.w;
            float4 wv = *(const float4*)&We[(size_t)(n0 + r) * FRAME_ + k0 + c4];
            Ws[c4 + 0][r] = wv.x; Ws[c4 + 1][r] = wv.y;
            Ws[c4 + 2][r] = wv.z; Ws[c4 + 3][r] = wv.w;
        }
        __syncthreads();
#pragma unroll
        for (int k = 0; k < 32; ++k) {
            float4 av = *(const float4*)&Xs[k][ty * 4];
            float4 bv = *(const float4*)&Ws[k][tx * 4];
            const float a[4] = {av.x, av.y, av.z, av.w};
            const float b[4] = {bv.x, bv.y, bv.z, bv.w};
#pragma unroll
            for (int i = 0; i < 4; ++i)
#pragma unroll
                for (int j = 0; j < 4; ++j)
                    acc[i][j] = fmaf(a[i], b[j], acc[i][j]);
        }
    }

    const int nb = n0 + tx * 4;
    const float4 bev = *(const float4*)&be[nb];
#pragma unroll
    for (int i = 0; i < 4; ++i) {
        const int m = m0 + ty * 4 + i;
        const int t = m % T_;
        const int bb = m / T_;
        float o[4];
        o[0] = acc[i][0] + bev.x; o[1] = acc[i][1] + bev.y;
        o[2] = acc[i][2] + bev.z; o[3] = acc[i][3] + bev.w;
        u16 hi[4], lo[4];
#pragma unroll
        for (int j = 0; j < 4; ++j) {
            hi[j] = f2bf_rn(o[j]);
            lo[j] = f2bf_rn(o[j] - bf2f(hi[j]));
        }
        const size_t off = ((size_t)t * B_ + bb) * PROJ_ + nb;
        *(uint2*)&vhi[off] = make_uint2((unsigned)hi[0] | ((unsigned)hi[1] << 16),
                                        (unsigned)hi[2] | ((unsigned)hi[3] << 16));
        *(uint2*)&vlo[off] = make_uint2((unsigned)lo[0] | ((unsigned)lo[1] << 16),
                                        (unsigned)lo[2] | ((unsigned)lo[3] << 16));
    }
}

// ---------------------------------------------------------------------------
// W presplit: rows reordered to n = by*128 + h_local*4 + gate, K = [ih | hh]
// ---------------------------------------------------------------------------
__global__ void wsplit_kernel(const float* __restrict__ Wih, const float* __restrict__ Whh,
                              u16* __restrict__ Whi, u16* __restrict__ Wlo)
{
    const int idx = blockIdx.x * 256 + threadIdx.x;   // 1572864 total
    const int e = idx * 4;
    const int n = e / 1536, k = e % 1536;
    const int g = n & 3;
    const int hg = (n >> 7) * 32 + ((n & 127) >> 2);
    const int srow = g * HID_ + hg;
    float4 f4 = (k < 512) ? *(const float4*)&Wih[(size_t)srow * PROJ_ + k]
                          : *(const float4*)&Whh[(size_t)srow * HID_ + (k - 512)];
    const float fs[4] = {f4.x, f4.y, f4.z, f4.w};
    u16 hi[4], lo[4];
#pragma unroll
    for (int j = 0; j < 4; ++j) {
        hi[j] = f2bf_rn(fs[j]);
        lo[j] = f2bf_rn(fs[j] - bf2f(hi[j]));
    }
    *(uint2*)&Whi[e] = make_uint2((unsigned)hi[0] | ((unsigned)hi[1] << 16),
                                  (unsigned)hi[2] | ((unsigned)hi[3] << 16));
    *(uint2*)&Wlo[e] = make_uint2((unsigned)lo[0] | ((unsigned)lo[1] << 16),
                                  (unsigned)lo[2] | ((unsigned)lo[3] << 16));
}

// ---------------------------------------------------------------------------
// boundary detector: keep[b] = (logit(b) > 0) ? 0 : 1
// vt reconstructed from hi+lo; fp64 accumulation.
// ---------------------------------------------------------------------------
__global__ __launch_bounds__(256)
void bd_kernel(const u16* __restrict__ vthi, const u16* __restrict__ vtlo,
               const float* __restrict__ h1i,
               const float* __restrict__ Wsi, const float* __restrict__ Wsh,
               const float* __restrict__ bbd, const float* __restrict__ vs,
               float* __restrict__ keep)
{
    __shared__ float xs[4][1536];
    __shared__ double red[4][128];
    const int tid = threadIdx.x;
    const int b0  = blockIdx.x * 4;

    for (int idx = tid; idx < 512; idx += 256) {
        const int r = idx >> 7, c = (idx & 127) << 2;
        const size_t o = (size_t)(b0 + r) * PROJ_ + c;
        const uint2 hv = *(const uint2*)&vthi[o];
        const uint2 lv = *(const uint2*)&vtlo[o];
        xs[r][c + 0] = bf2f((u16)hv.x)         + bf2f((u16)lv.x);
        xs[r][c + 1] = bf2f((u16)(hv.x >> 16)) + bf2f((u16)(lv.x >> 16));
        xs[r][c + 2] = bf2f((u16)hv.y)         + bf2f((u16)(lv.y));
        xs[r][c + 3] = bf2f((u16)(hv.y >> 16)) + bf2f((u16)(lv.y >> 16));
    }
    for (int idx = tid; idx < 1024; idx += 256) {
        const int r = idx >> 8, c = (idx & 255) << 2;
        *(float4*)&xs[r][512 + c] = *(const float4*)&h1i[(size_t)(b0 + r) * HID_ + c];
    }
    __syncthreads();

    const int mi = tid & 127;
    const int rg = tid >> 7;
    const int r0 = rg * 2, r1 = r0 + 1;

    double a0 = (double)bbd[mi], a1 = a0;

    const float4* wi4 = (const float4*)&Wsi[(size_t)mi * PROJ_];
    for (int k4 = 0; k4 < PROJ_ / 4; ++k4) {
        const float4 w = wi4[k4];
        const int k = k4 * 4;
        a0 += (double)w.x * xs[r0][k + 0] + (double)w.y * xs[r0][k + 1]
            + (double)w.z * xs[r0][k + 2] + (double)w.w * xs[r0][k + 3];
        a1 += (double)w.x * xs[r1][k + 0] + (double)w.y * xs[r1][k + 1]
            + (double)w.z * xs[r1][k + 2] + (double)w.w * xs[r1][k + 3];
    }
    const float4* wh4 = (const float4*)&Wsh[(size_t)mi * HID_];
    for (int k4 = 0; k4 < HID_ / 4; ++k4) {
        const float4 w = wh4[k4];
        const int k = 512 + k4 * 4;
        a0 += (double)w.x * xs[r0][k + 0] + (double)w.y * xs[r0][k + 1]
            + (double)w.z * xs[r0][k + 2] + (double)w.w * xs[r0][k + 3];
        a1 += (double)w.x * xs[r1][k + 0] + (double)w.y * xs[r1][k + 1]
            + (double)w.z * xs[r1][k + 2] + (double)w.w * xs[r1][k + 3];
    }
    const double vsm = (double)vs[mi];
    red[r0][mi] = vsm * a0;
    red[r1][mi] = vsm * a1;
    __syncthreads();

    if (tid < 4) {
        double s = 0.0;
        for (int i = 0; i < 128; ++i) s += red[tid][i];
        keep[b0 + tid] = (s > 0.0) ? 0.0f : 1.0f;
    }
}

// ---------------------------------------------------------------------------
// LSTM1 step, split-bf16 MFMA. BM=64, BN=128, BK=32, 4 waves, grid 256.
// LDS (per buf, 24 KB): [Ahi 4K | Alo 4K | Bhi 8K | Blo 8K], k-octet-major:
// A granule = koct*64 + m ; B granule = koct*128 + n   (16 B granules)
// ---------------------------------------------------------------------------
__global__ __launch_bounds__(256, 1)
void lstm_mfma_kernel(const u16* __restrict__ vthi, const u16* __restrict__ vtlo,
                      const u16* __restrict__ hhi,  const u16* __restrict__ hlo,
                      const u16* __restrict__ Whi,  const u16* __restrict__ Wlo,
                      const float* __restrict__ b1, const float* __restrict__ keep,
                      float* __restrict__ c1, float* __restrict__ h1o,
                      u16* __restrict__ hhio, u16* __restrict__ hloo)
{
    __shared__ char smem[49152];
    const int tid = threadIdx.x;
    const int w   = tid >> 6;
    const int l   = tid & 63;
    const int bid = blockIdx.x;
    const int xcd = bid & 7, slot = bid >> 3;
    const int by  = xcd * 4 + (slot & 3);   // 8 bx-blocks sharing a W-tile -> same XCD
    const int bx  = slot >> 2;
    const int b0  = bx * 64;
    const int n0  = by * 128;

    // per-lane staging sources
    const int koB = w >> 1;
    const int nB  = (w & 1) * 64 + l;
    const char* ws0 = (const char*)Whi + (size_t)(n0 + nB) * 3072 + koB * 16;
    const char* ws1 = ws0 + 32;
    const char* ws2 = (const char*)Wlo + (size_t)(n0 + nB) * 3072 + koB * 16;
    const char* ws3 = ws2 + 32;
    const char* ahS = (const char*)vthi + (size_t)(b0 + l) * 1024 + w * 16;
    const char* alS = (const char*)vtlo + (size_t)(b0 + l) * 1024 + w * 16;

    auto stage = [&](int buf) {
        char* base = smem + buf * 24576 + w * 1024;
        gld16(ahS, base + 0);
        gld16(alS, base + 4096);
        gld16(ws0, base + 8192);
        gld16(ws1, base + 12288);
        gld16(ws2, base + 16384);
        gld16(ws3, base + 20480);
        ahS += 64; alS += 64; ws0 += 64; ws1 += 64; ws2 += 64; ws3 += 64;
    };

    f32x4 acc[4][2] = {};
    stage(0);
    __syncthreads();
    int cur = 0;
    const int lm = l & 15, ko = l >> 4;

    for (int kk = 0; kk < 48; ++kk) {
        if (kk + 1 == 16) {   // switch A source: vt (k<512) -> h (k>=512)
            ahS = (const char*)hhi + (size_t)(b0 + l) * 2048 + w * 16;
            alS = (const char*)hlo + (size_t)(b0 + l) * 2048 + w * 16;
        }
        if (kk + 1 < 48) stage(cur ^ 1);

        const char* base = smem + cur * 24576;
        bf16x8 Ahi[4], Alo[4], Bhi[2], Blo[2];
#pragma unroll
        for (int mt = 0; mt < 4; ++mt) {
            const int m = mt * 16 + lm;
            Ahi[mt] = *(const bf16x8*)(base + (ko * 64 + m) * 16);
            Alo[mt] = *(const bf16x8*)(base + 4096 + (ko * 64 + m) * 16);
        }
#pragma unroll
        for (int nt = 0; nt < 2; ++nt) {
            const int n = (w * 2 + nt) * 16 + lm;
            Bhi[nt] = *(const bf16x8*)(base + 8192  + (ko * 128 + n) * 16);
            Blo[nt] = *(const bf16x8*)(base + 16384 + (ko * 128 + n) * 16);
        }
#pragma unroll
        for (int mt = 0; mt < 4; ++mt)
#pragma unroll
            for (int nt = 0; nt < 2; ++nt) {
                acc[mt][nt] = __builtin_amdgcn_mfma_f32_16x16x32_bf16(Ahi[mt], Bhi[nt], acc[mt][nt], 0, 0, 0);
                acc[mt][nt] = __builtin_amdgcn_mfma_f32_16x16x32_bf16(Ahi[mt], Blo[nt], acc[mt][nt], 0, 0, 0);
                acc[mt][nt] = __builtin_amdgcn_mfma_f32_16x16x32_bf16(Alo[mt], Bhi[nt], acc[mt][nt], 0, 0, 0);
            }
        __syncthreads();
        cur ^= 1;
    }

    // epilogue: exchange via LDS so each thread owns 4 gates of (b, h)
    float* S = (float*)smem;   // [64][132] padded
#pragma unroll
    for (int mt = 0; mt < 4; ++mt)
#pragma unroll
        for (int nt = 0; nt < 2; ++nt) {
            const int n = (w * 2 + nt) * 16 + lm;
#pragma unroll
            for (int r = 0; r < 4; ++r) {
                const int m = mt * 16 + ko * 4 + r;
                S[m * 132 + n] = acc[mt][nt][r];
            }
        }
    __syncthreads();

    const int h_l = tid & 31, mg = tid >> 5;
    const int hg  = by * 32 + h_l;
    const float bI = b1[hg], bF = b1[HID_ + hg], bG = b1[2 * HID_ + hg], bO = b1[3 * HID_ + hg];
#pragma unroll
    for (int i = 0; i < 8; ++i) {
        const int m = mg * 8 + i;
        const int b = b0 + m;
        const float4 g4 = *(const float4*)&S[m * 132 + h_l * 4];
        const float i_ = sigmoidf_(g4.x + bI);
        const float f_ = sigmoidf_(g4.y + bF);
        const float g_ = tanhf(g4.z + bG);
        const float o_ = sigmoidf_(g4.w + bO);
        const size_t off = (size_t)b * HID_ + hg;
        float cn = f_ * c1[off] + i_ * g_;
        float hn = o_ * tanhf(cn);
        const float kp = keep[b];
        cn *= kp; hn *= kp;
        c1[off]  = cn;
        h1o[off] = hn;
        const u16 hb = f2bf_rn(hn);
        hhio[off] = hb;
        hloo[off] = f2bf_rn(hn - bf2f(hb));
    }
}

__global__ void b1sum_kernel(const float* __restrict__ bih,
                             const float* __restrict__ bhh,
                             float* __restrict__ b1)
{
    const int i = blockIdx.x * 256 + threadIdx.x;
    if (i < G4_) b1[i] = bih[i] + bhh[i];
}

// ---------------------------------------------------------------------------
extern "C" void kernel_launch(void* const* d_in, const int* in_sizes, int n_in,
                              void* d_out, int out_size, void* d_ws, size_t ws_size,
                              hipStream_t stream)
{
    const float* video = (const float*)d_in[0];
    const float* We    = (const float*)d_in[1];
    const float* be    = (const float*)d_in[2];
    const float* W1_ih = (const float*)d_in[3];
    const float* W1_hh = (const float*)d_in[4];
    const float* b1_ih = (const float*)d_in[5];
    const float* b1_hh = (const float*)d_in[6];
    // d_in[7], d_in[8] (W2_ih, W2_hh): dead — lstm2 never affects the output
    const float* Wsi   = (const float*)d_in[9];
    const float* Wsh   = (const float*)d_in[10];
    const float* bbd   = (const float*)d_in[11];
    const float* vs    = (const float*)d_in[12];
    float* out = (float*)d_out;

    char* p = (char*)d_ws;
    u16* vhi = (u16*)p;            p += (size_t)T_ * B_ * PROJ_ * 2;   // 25.2 MB
    u16* vlo = (u16*)p;            p += (size_t)T_ * B_ * PROJ_ * 2;
    u16* Whi = (u16*)p;            p += (size_t)G4_ * 1536 * 2;        // 12.6 MB
    u16* Wlo = (u16*)p;            p += (size_t)G4_ * 1536 * 2;
    float* h1a  = (float*)p;       p += (size_t)B_ * HID_ * 4;
    float* h1b  = (float*)p;       p += (size_t)B_ * HID_ * 4;
    float* c1   = (float*)p;       p += (size_t)B_ * HID_ * 4;
    u16* hhiA = (u16*)p;           p += (size_t)B_ * HID_ * 2;
    u16* hhiB = (u16*)p;           p += (size_t)B_ * HID_ * 2;
    u16* hloA = (u16*)p;           p += (size_t)B_ * HID_ * 2;
    u16* hloB = (u16*)p;           p += (size_t)B_ * HID_ * 2;
    float* keep = (float*)p;       p += B_ * 4;
    float* b1   = (float*)p;       p += G4_ * 4;

    hipMemsetAsync(h1a,  0, (size_t)B_ * HID_ * 4, stream);
    hipMemsetAsync(c1,   0, (size_t)B_ * HID_ * 4, stream);
    hipMemsetAsync(hhiA, 0, (size_t)B_ * HID_ * 2, stream);
    hipMemsetAsync(hloA, 0, (size_t)B_ * HID_ * 2, stream);

    b1sum_kernel<<<16, 256, 0, stream>>>(b1_ih, b1_hh, b1);
    wsplit_kernel<<<6144, 256, 0, stream>>>(W1_ih, W1_hh, Whi, Wlo);
    embed_kernel<<<dim3(384, 8), 256, 0, stream>>>(video, We, be, vhi, vlo);

    float* hin  = h1a; float* hout = h1b;
    u16* hhi_in = hhiA; u16* hhi_out = hhiB;
    u16* hlo_in = hloA; u16* hlo_out = hloB;

    for (int t = 0; t < T_; ++t) {
        const u16* vthi = vhi + (size_t)t * B_ * PROJ_;
        const u16* vtlo = vlo + (size_t)t * B_ * PROJ_;
        bd_kernel<<<128, 256, 0, stream>>>(vthi, vtlo, hin, Wsi, Wsh, bbd, vs, keep);
        float* ho = (t == T_ - 1) ? out : hout;
        lstm_mfma_kernel<<<256, 256, 0, stream>>>(vthi, vtlo, hhi_in, hlo_in,
                                                  Whi, Wlo, b1, keep, c1,
                                                  ho, hhi_out, hlo_out);
        { float* tmp = hin; hin = hout; hout = tmp; }
        { u16* tmp = hhi_in; hhi_in = hhi_out; hhi_out = tmp; }
        { u16* tmp = hlo_in; hlo_in = hlo_out; hlo_out = tmp; }
    }
}

// Round 3
// 3696.803 us; speedup vs baseline: 2.2505x; 1.6368x over previous
//
#include <hip/hip_runtime.h>

#define B_     512
#define T_     48
#define FRAME_ 2048
#define PROJ_  512
#define MID_   128
#define HID_   1024
#define G4_    4096

typedef unsigned short u16;
typedef __bf16 bf16x8 __attribute__((ext_vector_type(8)));
typedef float  f32x4  __attribute__((ext_vector_type(4)));

__device__ __forceinline__ float sigmoidf_(float x) {
    return 1.0f / (1.0f + expf(-x));
}
__device__ __forceinline__ u16 f2bf_rn(float f) {
    unsigned int u = __float_as_uint(f);
    u += 0x7fffu + ((u >> 16) & 1u);
    return (u16)(u >> 16);
}
__device__ __forceinline__ float bf2f(u16 s) {
    return __uint_as_float(((unsigned int)s) << 16);
}
__device__ __forceinline__ void gld16(const void* g, void* l) {
    __builtin_amdgcn_global_load_lds((const __attribute__((address_space(1))) void*)g,
                                     (__attribute__((address_space(3))) void*)l, 16, 0, 0);
}

// ---------------------------------------------------------------------------
// BD linearization precompute:
//   wsi_v[p] = sum_mi vs[mi]*Wsi[mi][p]   (fp64, kept as double)
//   wsh_v[k] = sum_mi vs[mi]*Wsh[mi][k]   (fp32 for epilogue use)
//   cc = be·wsi_v + vs·bbd
//   u[f] = sum_p wsi_v[p]*We[p][f]        (fp64)
//   Lv[t][b] = video[b][t][:]·u + cc      (fp64 accum -> fp32)
// ---------------------------------------------------------------------------
__global__ void wvec_kernel(const float* __restrict__ Wsi, const float* __restrict__ Wsh,
                            const float* __restrict__ vs,
                            double* __restrict__ wsi_vd, float* __restrict__ wsh_v)
{
    const int gid = blockIdx.x * 256 + threadIdx.x;
    if (gid < 512) {
        double s = 0.0;
        for (int mi = 0; mi < MID_; ++mi)
            s += (double)vs[mi] * (double)Wsi[(size_t)mi * PROJ_ + gid];
        wsi_vd[gid] = s;
    } else if (gid < 1536) {
        const int k = gid - 512;
        double s = 0.0;
        for (int mi = 0; mi < MID_; ++mi)
            s += (double)vs[mi] * (double)Wsh[(size_t)mi * HID_ + k];
        wsh_v[k] = (float)s;
    }
}

__global__ void cc_kernel(const float* __restrict__ be, const double* __restrict__ wsi_vd,
                          const float* __restrict__ vs, const float* __restrict__ bbd,
                          double* __restrict__ cc)
{
    __shared__ double red[256];
    const int tid = threadIdx.x;
    double s = 0.0;
    for (int p = tid; p < PROJ_; p += 256) s += (double)be[p] * wsi_vd[p];
    red[tid] = s;
    __syncthreads();
    for (int st = 128; st > 0; st >>= 1) {
        if (tid < st) red[tid] += red[tid + st];
        __syncthreads();
    }
    if (tid == 0) {
        double b = 0.0;
        for (int mi = 0; mi < MID_; ++mi) b += (double)vs[mi] * (double)bbd[mi];
        cc[0] = red[0] + b;
    }
}

__global__ void u_kernel(const float* __restrict__ We, const double* __restrict__ wsi_vd,
                         double* __restrict__ u)
{
    const int f = blockIdx.x * 256 + threadIdx.x;   // 2048
    double s = 0.0;
    for (int p = 0; p < PROJ_; ++p)
        s += wsi_vd[p] * (double)We[(size_t)p * FRAME_ + f];
    u[f] = s;
}

__global__ __launch_bounds__(256)
void lv_kernel(const float* __restrict__ video, const double* __restrict__ u,
               const double* __restrict__ cc, float* __restrict__ Lv)
{
    const int tid = threadIdx.x;
    const int row = blockIdx.x * 4 + (tid >> 6);    // row = b*T + t
    const int j   = tid & 63;
    const float* vr = video + (size_t)row * FRAME_;
    double s = 0.0;
#pragma unroll
    for (int it = 0; it < 8; ++it) {
        const int e = it * 256 + j * 4;
        const float4 xv = *(const float4*)&vr[e];
        s += (double)xv.x * u[e + 0] + (double)xv.y * u[e + 1]
           + (double)xv.z * u[e + 2] + (double)xv.w * u[e + 3];
    }
#pragma unroll
    for (int m = 32; m > 0; m >>= 1) s += __shfl_xor(s, m);
    if (j == 0) {
        const int b = row / T_, t = row % T_;
        Lv[t * B_ + b] = (float)(s + cc[0]);
    }
}

// ---------------------------------------------------------------------------
// embed: v[t][b][p] = video[b][t][:] . We[p][:] + be[p]  -> split bf16 hi/lo
// ---------------------------------------------------------------------------
__global__ __launch_bounds__(256, 2)
void embed_kernel(const float* __restrict__ video, const float* __restrict__ We,
                  const float* __restrict__ be,
                  u16* __restrict__ vhi, u16* __restrict__ vlo)
{
    __shared__ float Xs[32][68];
    __shared__ float Ws[32][68];
    const int m0  = blockIdx.x * 64;
    const int n0  = blockIdx.y * 64;
    const int tid = threadIdx.x;
    const int tx  = tid & 15, ty = tid >> 4;
    const int lr  = tid >> 3;
    const int c4  = (tid & 7) * 4;

    float acc[4][4] = {};

    for (int kt = 0; kt < FRAME_ / 32; ++kt) {
        const int k0 = kt * 32;
        __syncthreads();
#pragma unroll
        for (int rep = 0; rep < 2; ++rep) {
            const int r = lr + rep * 32;
            float4 xv = *(const float4*)&video[(size_t)(m0 + r) * FRAME_ + k0 + c4];
            Xs[c4 + 0][r] = xv.x; Xs[c4 + 1][r] = xv.y;
            Xs[c4 + 2][r] = xv.z; Xs[c4 + 3][r] = xv.w;
            float4 wv = *(const float4*)&We[(size_t)(n0 + r) * FRAME_ + k0 + c4];
            Ws[c4 + 0][r] = wv.x; Ws[c4 + 1][r] = wv.y;
            Ws[c4 + 2][r] = wv.z; Ws[c4 + 3][r] = wv.w;
        }
        __syncthreads();
#pragma unroll
        for (int k = 0; k < 32; ++k) {
            float4 av = *(const float4*)&Xs[k][ty * 4];
            float4 bv = *(const float4*)&Ws[k][tx * 4];
            const float a[4] = {av.x, av.y, av.z, av.w};
            const float b[4] = {bv.x, bv.y, bv.z, bv.w};
#pragma unroll
            for (int i = 0; i < 4; ++i)
#pragma unroll
                for (int j = 0; j < 4; ++j)
                    acc[i][j] = fmaf(a[i], b[j], acc[i][j]);
        }
    }

    const int nb = n0 + tx * 4;
    const float4 bev = *(const float4*)&be[nb];
#pragma unroll
    for (int i = 0; i < 4; ++i) {
        const int m = m0 + ty * 4 + i;
        const int t = m % T_;
        const int bb = m / T_;
        float o[4];
        o[0] = acc[i][0] + bev.x; o[1] = acc[i][1] + bev.y;
        o[2] = acc[i][2] + bev.z; o[3] = acc[i][3] + bev.w;
        u16 hi[4], lo[4];
#pragma unroll
        for (int j = 0; j < 4; ++j) {
            hi[j] = f2bf_rn(o[j]);
            lo[j] = f2bf_rn(o[j] - bf2f(hi[j]));
        }
        const size_t off = ((size_t)t * B_ + bb) * PROJ_ + nb;
        *(uint2*)&vhi[off] = make_uint2((unsigned)hi[0] | ((unsigned)hi[1] << 16),
                                        (unsigned)hi[2] | ((unsigned)hi[3] << 16));
        *(uint2*)&vlo[off] = make_uint2((unsigned)lo[0] | ((unsigned)lo[1] << 16),
                                        (unsigned)lo[2] | ((unsigned)lo[3] << 16));
    }
}

// ---------------------------------------------------------------------------
// W presplit: rows reordered to n = by*128 + h_local*4 + gate, K = [ih | hh]
// ---------------------------------------------------------------------------
__global__ void wsplit_kernel(const float* __restrict__ Wih, const float* __restrict__ Whh,
                              u16* __restrict__ Whi, u16* __restrict__ Wlo)
{
    const int idx = blockIdx.x * 256 + threadIdx.x;
    const int e = idx * 4;
    const int n = e / 1536, k = e % 1536;
    const int g = n & 3;
    const int hg = (n >> 7) * 32 + ((n & 127) >> 2);
    const int srow = g * HID_ + hg;
    float4 f4 = (k < 512) ? *(const float4*)&Wih[(size_t)srow * PROJ_ + k]
                          : *(const float4*)&Whh[(size_t)srow * HID_ + (k - 512)];
    const float fs[4] = {f4.x, f4.y, f4.z, f4.w};
    u16 hi[4], lo[4];
#pragma unroll
    for (int j = 0; j < 4; ++j) {
        hi[j] = f2bf_rn(fs[j]);
        lo[j] = f2bf_rn(fs[j] - bf2f(hi[j]));
    }
    *(uint2*)&Whi[e] = make_uint2((unsigned)hi[0] | ((unsigned)hi[1] << 16),
                                  (unsigned)hi[2] | ((unsigned)hi[3] << 16));
    *(uint2*)&Wlo[e] = make_uint2((unsigned)lo[0] | ((unsigned)lo[1] << 16),
                                  (unsigned)lo[2] | ((unsigned)lo[3] << 16));
}

// ---------------------------------------------------------------------------
// LSTM1 step, split-bf16 MFMA. BM=64, BN=128, BK=32, 4 waves, grid 256.
// Fused: prologue computes keep[b] from Pin+Lv (BD linearized);
// epilogue emits Pout partials (h·wsh_v per 32-h slice, shuffle-reduced).
// ---------------------------------------------------------------------------
__global__ __launch_bounds__(256, 1)
void lstm_mfma_kernel(const u16* __restrict__ vthi, const u16* __restrict__ vtlo,
                      const u16* __restrict__ hhi,  const u16* __restrict__ hlo,
                      const u16* __restrict__ Whi,  const u16* __restrict__ Wlo,
                      const float* __restrict__ b1,
                      const float* __restrict__ Lv_t,
                      const float* __restrict__ Pin,
                      float* __restrict__ Pout,
                      const float* __restrict__ wsh_v,
                      float* __restrict__ c1, float* __restrict__ h1o,
                      u16* __restrict__ hhio, u16* __restrict__ hloo)
{
    __shared__ char smem[49408];
    float* keepsm = (float*)(smem + 49152);
    const int tid = threadIdx.x;
    const int w   = tid >> 6;
    const int l   = tid & 63;
    const int bid = blockIdx.x;
    const int xcd = bid & 7, slot = bid >> 3;
    const int by  = xcd * 4 + (slot & 3);
    const int bx  = slot >> 2;
    const int b0  = bx * 64;
    const int n0  = by * 128;

    const int koB = w >> 1;
    const int nB  = (w & 1) * 64 + l;
    const char* ws0 = (const char*)Whi + (size_t)(n0 + nB) * 3072 + koB * 16;
    const char* ws1 = ws0 + 32;
    const char* ws2 = (const char*)Wlo + (size_t)(n0 + nB) * 3072 + koB * 16;
    const char* ws3 = ws2 + 32;
    const char* ahS = (const char*)vthi + (size_t)(b0 + l) * 1024 + w * 16;
    const char* alS = (const char*)vtlo + (size_t)(b0 + l) * 1024 + w * 16;

    auto stage = [&](int buf) {
        char* base = smem + buf * 24576 + w * 1024;
        gld16(ahS, base + 0);
        gld16(alS, base + 4096);
        gld16(ws0, base + 8192);
        gld16(ws1, base + 12288);
        gld16(ws2, base + 16384);
        gld16(ws3, base + 20480);
        ahS += 64; alS += 64; ws0 += 64; ws1 += 64; ws2 += 64; ws3 += 64;
    };

    f32x4 acc[4][2] = {};
    stage(0);

    // keep[b] = (Lv[t][b] + sum_j Pin[j][b] > 0) ? 0 : 1
    if (tid < 64) {
        double s = (double)Lv_t[b0 + tid];
#pragma unroll
        for (int j = 0; j < 32; ++j) s += (double)Pin[j * B_ + b0 + tid];
        keepsm[tid] = (s > 0.0) ? 0.0f : 1.0f;
    }
    __syncthreads();

    int cur = 0;
    const int lm = l & 15, ko = l >> 4;

    for (int kk = 0; kk < 48; ++kk) {
        if (kk + 1 == 16) {
            ahS = (const char*)hhi + (size_t)(b0 + l) * 2048 + w * 16;
            alS = (const char*)hlo + (size_t)(b0 + l) * 2048 + w * 16;
        }
        if (kk + 1 < 48) stage(cur ^ 1);

        const char* base = smem + cur * 24576;
        bf16x8 Ahi[4], Alo[4], Bhi[2], Blo[2];
#pragma unroll
        for (int mt = 0; mt < 4; ++mt) {
            const int m = mt * 16 + lm;
            Ahi[mt] = *(const bf16x8*)(base + (ko * 64 + m) * 16);
            Alo[mt] = *(const bf16x8*)(base + 4096 + (ko * 64 + m) * 16);
        }
#pragma unroll
        for (int nt = 0; nt < 2; ++nt) {
            const int n = (w * 2 + nt) * 16 + lm;
            Bhi[nt] = *(const bf16x8*)(base + 8192  + (ko * 128 + n) * 16);
            Blo[nt] = *(const bf16x8*)(base + 16384 + (ko * 128 + n) * 16);
        }
#pragma unroll
        for (int mt = 0; mt < 4; ++mt)
#pragma unroll
            for (int nt = 0; nt < 2; ++nt) {
                acc[mt][nt] = __builtin_amdgcn_mfma_f32_16x16x32_bf16(Ahi[mt], Bhi[nt], acc[mt][nt], 0, 0, 0);
                acc[mt][nt] = __builtin_amdgcn_mfma_f32_16x16x32_bf16(Ahi[mt], Blo[nt], acc[mt][nt], 0, 0, 0);
                acc[mt][nt] = __builtin_amdgcn_mfma_f32_16x16x32_bf16(Alo[mt], Bhi[nt], acc[mt][nt], 0, 0, 0);
            }
        __syncthreads();
        cur ^= 1;
    }

    // epilogue: exchange via LDS so each thread owns 4 gates of (b, h)
    float* S = (float*)smem;   // [64][132]
#pragma unroll
    for (int mt = 0; mt < 4; ++mt)
#pragma unroll
        for (int nt = 0; nt < 2; ++nt) {
            const int n = (w * 2 + nt) * 16 + lm;
#pragma unroll
            for (int r = 0; r < 4; ++r) {
                const int m = mt * 16 + ko * 4 + r;
                S[m * 132 + n] = acc[mt][nt][r];
            }
        }
    __syncthreads();

    const int h_l = tid & 31, mg = tid >> 5;
    const int hg  = by * 32 + h_l;
    const float bI = b1[hg], bF = b1[HID_ + hg], bG = b1[2 * HID_ + hg], bO = b1[3 * HID_ + hg];
    const float wv = wsh_v[hg];
#pragma unroll
    for (int i = 0; i < 8; ++i) {
        const int m = mg * 8 + i;
        const int b = b0 + m;
        const float4 g4 = *(const float4*)&S[m * 132 + h_l * 4];
        const float i_ = sigmoidf_(g4.x + bI);
        const float f_ = sigmoidf_(g4.y + bF);
        const float g_ = tanhf(g4.z + bG);
        const float o_ = sigmoidf_(g4.w + bO);
        const size_t off = (size_t)b * HID_ + hg;
        float cn = f_ * c1[off] + i_ * g_;
        float hn = o_ * tanhf(cn);
        const float kp = keepsm[m];
        cn *= kp; hn *= kp;
        c1[off] = cn;
        if (h1o) h1o[off] = hn;
        const u16 hb = f2bf_rn(hn);
        hhio[off] = hb;
        hloo[off] = f2bf_rn(hn - bf2f(hb));
        // Pout[by][b] = sum over this block's 32 h of hn*wsh_v
        float pr = hn * wv;
        pr += __shfl_xor(pr, 16);
        pr += __shfl_xor(pr, 8);
        pr += __shfl_xor(pr, 4);
        pr += __shfl_xor(pr, 2);
        pr += __shfl_xor(pr, 1);
        if (h_l == 0) Pout[by * B_ + b] = pr;
    }
}

__global__ void b1sum_kernel(const float* __restrict__ bih,
                             const float* __restrict__ bhh,
                             float* __restrict__ b1)
{
    const int i = blockIdx.x * 256 + threadIdx.x;
    if (i < G4_) b1[i] = bih[i] + bhh[i];
}

// ---------------------------------------------------------------------------
extern "C" void kernel_launch(void* const* d_in, const int* in_sizes, int n_in,
                              void* d_out, int out_size, void* d_ws, size_t ws_size,
                              hipStream_t stream)
{
    const float* video = (const float*)d_in[0];
    const float* We    = (const float*)d_in[1];
    const float* be    = (const float*)d_in[2];
    const float* W1_ih = (const float*)d_in[3];
    const float* W1_hh = (const float*)d_in[4];
    const float* b1_ih = (const float*)d_in[5];
    const float* b1_hh = (const float*)d_in[6];
    // d_in[7], d_in[8] (W2_ih, W2_hh): dead — lstm2 never affects the output
    const float* Wsi   = (const float*)d_in[9];
    const float* Wsh   = (const float*)d_in[10];
    const float* bbd   = (const float*)d_in[11];
    const float* vs    = (const float*)d_in[12];
    float* out = (float*)d_out;

    char* p = (char*)d_ws;
    u16* vhi = (u16*)p;            p += (size_t)T_ * B_ * PROJ_ * 2;
    u16* vlo = (u16*)p;            p += (size_t)T_ * B_ * PROJ_ * 2;
    u16* Whi = (u16*)p;            p += (size_t)G4_ * 1536 * 2;
    u16* Wlo = (u16*)p;            p += (size_t)G4_ * 1536 * 2;
    double* wsi_vd = (double*)p;   p += 512 * 8;
    double* u      = (double*)p;   p += 2048 * 8;
    double* cc     = (double*)p;   p += 8;
    float* c1   = (float*)p;       p += (size_t)B_ * HID_ * 4;
    u16* hhiA = (u16*)p;           p += (size_t)B_ * HID_ * 2;
    u16* hhiB = (u16*)p;           p += (size_t)B_ * HID_ * 2;
    u16* hloA = (u16*)p;           p += (size_t)B_ * HID_ * 2;
    u16* hloB = (u16*)p;           p += (size_t)B_ * HID_ * 2;
    float* wsh_v = (float*)p;      p += 1024 * 4;
    float* Lv    = (float*)p;      p += (size_t)T_ * B_ * 4;
    float* PA    = (float*)p;      p += 32 * B_ * 4;
    float* PB    = (float*)p;      p += 32 * B_ * 4;
    float* b1    = (float*)p;      p += G4_ * 4;

    hipMemsetAsync(c1,   0, (size_t)B_ * HID_ * 4, stream);
    hipMemsetAsync(hhiA, 0, (size_t)B_ * HID_ * 2, stream);
    hipMemsetAsync(hloA, 0, (size_t)B_ * HID_ * 2, stream);
    hipMemsetAsync(PA,   0, 32 * B_ * 4, stream);

    b1sum_kernel<<<16, 256, 0, stream>>>(b1_ih, b1_hh, b1);
    wvec_kernel<<<6, 256, 0, stream>>>(Wsi, Wsh, vs, wsi_vd, wsh_v);
    cc_kernel<<<1, 256, 0, stream>>>(be, wsi_vd, vs, bbd, cc);
    u_kernel<<<8, 256, 0, stream>>>(We, wsi_vd, u);
    wsplit_kernel<<<6144, 256, 0, stream>>>(W1_ih, W1_hh, Whi, Wlo);
    embed_kernel<<<dim3(384, 8), 256, 0, stream>>>(video, We, be, vhi, vlo);
    lv_kernel<<<6144, 256, 0, stream>>>(video, u, cc, Lv);

    u16* hhi_in = hhiA; u16* hhi_out = hhiB;
    u16* hlo_in = hloA; u16* hlo_out = hloB;
    float* Pin = PA; float* Pout = PB;

    for (int t = 0; t < T_; ++t) {
        const u16* vthi = vhi + (size_t)t * B_ * PROJ_;
        const u16* vtlo = vlo + (size_t)t * B_ * PROJ_;
        float* ho = (t == T_ - 1) ? out : nullptr;
        lstm_mfma_kernel<<<256, 256, 0, stream>>>(vthi, vtlo, hhi_in, hlo_in,
                                                  Whi, Wlo, b1,
                                                  Lv + t * B_, Pin, Pout, wsh_v,
                                                  c1, ho, hhi_out, hlo_out);
        { u16* tmp = hhi_in; hhi_in = hhi_out; hhi_out = tmp; }
        { u16* tmp = hlo_in; hlo_in = hlo_out; hlo_out = tmp; }
        { float* tmp = Pin; Pin = Pout; Pout = tmp; }
    }
}

// Round 4
// 2841.947 us; speedup vs baseline: 2.9275x; 1.3008x over previous
//
#include <hip/hip_runtime.h>

#define B_     512
#define T_     48
#define FRAME_ 2048
#define PROJ_  512
#define MID_   128
#define HID_   1024
#define G4_    4096

typedef unsigned short u16;
typedef __bf16 bf16x8 __attribute__((ext_vector_type(8)));
typedef float  f32x4  __attribute__((ext_vector_type(4)));

__device__ __forceinline__ float sigmoidf_(float x) {
    return 1.0f / (1.0f + expf(-x));
}
__device__ __forceinline__ u16 f2bf_rn(float f) {
    unsigned int u = __float_as_uint(f);
    u += 0x7fffu + ((u >> 16) & 1u);
    return (u16)(u >> 16);
}
__device__ __forceinline__ float bf2f(u16 s) {
    return __uint_as_float(((unsigned int)s) << 16);
}
__device__ __forceinline__ void gld16(const void* g, void* l) {
    __builtin_amdgcn_global_load_lds((const __attribute__((address_space(1))) void*)g,
                                     (__attribute__((address_space(3))) void*)l, 16, 0, 0);
}

// ---------------------------------------------------------------------------
// BD linearization precompute (exact fp64 path)
// ---------------------------------------------------------------------------
__global__ void wvec_kernel(const float* __restrict__ Wsi, const float* __restrict__ Wsh,
                            const float* __restrict__ vs,
                            double* __restrict__ wsi_vd, float* __restrict__ wsh_v)
{
    const int gid = blockIdx.x * 256 + threadIdx.x;
    if (gid < 512) {
        double s = 0.0;
        for (int mi = 0; mi < MID_; ++mi)
            s += (double)vs[mi] * (double)Wsi[(size_t)mi * PROJ_ + gid];
        wsi_vd[gid] = s;
    } else if (gid < 1536) {
        const int k = gid - 512;
        double s = 0.0;
        for (int mi = 0; mi < MID_; ++mi)
            s += (double)vs[mi] * (double)Wsh[(size_t)mi * HID_ + k];
        wsh_v[k] = (float)s;
    }
}

__global__ void cc_kernel(const float* __restrict__ be, const double* __restrict__ wsi_vd,
                          const float* __restrict__ vs, const float* __restrict__ bbd,
                          double* __restrict__ cc)
{
    __shared__ double red[256];
    const int tid = threadIdx.x;
    double s = 0.0;
    for (int p = tid; p < PROJ_; p += 256) s += (double)be[p] * wsi_vd[p];
    red[tid] = s;
    __syncthreads();
    for (int st = 128; st > 0; st >>= 1) {
        if (tid < st) red[tid] += red[tid + st];
        __syncthreads();
    }
    if (tid == 0) {
        double b = 0.0;
        for (int mi = 0; mi < MID_; ++mi) b += (double)vs[mi] * (double)bbd[mi];
        cc[0] = red[0] + b;
    }
}

__global__ void u_kernel(const float* __restrict__ We, const double* __restrict__ wsi_vd,
                         double* __restrict__ u)
{
    const int f = blockIdx.x * 256 + threadIdx.x;   // 2048
    double s = 0.0;
    for (int p = 0; p < PROJ_; ++p)
        s += wsi_vd[p] * (double)We[(size_t)p * FRAME_ + f];
    u[f] = s;
}

__global__ __launch_bounds__(256)
void lv_kernel(const float* __restrict__ video, const double* __restrict__ u,
               const double* __restrict__ cc, float* __restrict__ Lv)
{
    const int tid = threadIdx.x;
    const int row = blockIdx.x * 4 + (tid >> 6);    // row = b*T + t
    const int j   = tid & 63;
    const float* vr = video + (size_t)row * FRAME_;
    double s = 0.0;
#pragma unroll
    for (int it = 0; it < 8; ++it) {
        const int e = it * 256 + j * 4;
        const float4 xv = *(const float4*)&vr[e];
        s += (double)xv.x * u[e + 0] + (double)xv.y * u[e + 1]
           + (double)xv.z * u[e + 2] + (double)xv.w * u[e + 3];
    }
#pragma unroll
    for (int m = 32; m > 0; m >>= 1) s += __shfl_xor(s, m);
    if (j == 0) {
        const int b = row / T_, t = row % T_;
        Lv[t * B_ + b] = (float)(s + cc[0]);
    }
}

// ---------------------------------------------------------------------------
// generic fp32 -> bf16 hi/lo split (used for We and video chunks)
// ---------------------------------------------------------------------------
__global__ void split_kernel(const float* __restrict__ src, u16* __restrict__ hi,
                             u16* __restrict__ lo, int n4)
{
    const int idx = blockIdx.x * 256 + threadIdx.x;
    if (idx >= n4) return;
    const float4 f4 = ((const float4*)src)[idx];
    const float fs[4] = {f4.x, f4.y, f4.z, f4.w};
    u16 h[4], l[4];
#pragma unroll
    for (int j = 0; j < 4; ++j) {
        h[j] = f2bf_rn(fs[j]);
        l[j] = f2bf_rn(fs[j] - bf2f(h[j]));
    }
    ((uint2*)hi)[idx] = make_uint2((unsigned)h[0] | ((unsigned)h[1] << 16),
                                   (unsigned)h[2] | ((unsigned)h[3] << 16));
    ((uint2*)lo)[idx] = make_uint2((unsigned)l[0] | ((unsigned)l[1] << 16),
                                   (unsigned)l[2] | ((unsigned)l[3] << 16));
}

// ---------------------------------------------------------------------------
// W1 presplit: rows reordered to n = by*128 + h_local*4 + gate, K = [ih | hh]
// ---------------------------------------------------------------------------
__global__ void wsplit_kernel(const float* __restrict__ Wih, const float* __restrict__ Whh,
                              u16* __restrict__ Whi, u16* __restrict__ Wlo)
{
    const int idx = blockIdx.x * 256 + threadIdx.x;
    const int e = idx * 4;
    const int n = e / 1536, k = e % 1536;
    const int g = n & 3;
    const int hg = (n >> 7) * 32 + ((n & 127) >> 2);
    const int srow = g * HID_ + hg;
    float4 f4 = (k < 512) ? *(const float4*)&Wih[(size_t)srow * PROJ_ + k]
                          : *(const float4*)&Whh[(size_t)srow * HID_ + (k - 512)];
    const float fs[4] = {f4.x, f4.y, f4.z, f4.w};
    u16 hi[4], lo[4];
#pragma unroll
    for (int j = 0; j < 4; ++j) {
        hi[j] = f2bf_rn(fs[j]);
        lo[j] = f2bf_rn(fs[j] - bf2f(hi[j]));
    }
    *(uint2*)&Whi[e] = make_uint2((unsigned)hi[0] | ((unsigned)hi[1] << 16),
                                  (unsigned)hi[2] | ((unsigned)hi[3] << 16));
    *(uint2*)&Wlo[e] = make_uint2((unsigned)lo[0] | ((unsigned)lo[1] << 16),
                                  (unsigned)lo[2] | ((unsigned)lo[3] << 16));
}

// ---------------------------------------------------------------------------
// embed GEMM, split-bf16 MFMA. BM=64, BN=128, BK=32, 8 waves (512 thr).
// A = video chunk hi/lo planes (rows chunk-local, 4096 B/row), B = We planes.
// Counted-vmcnt double-buffer pipeline, 2 raw barriers per K-step.
// ---------------------------------------------------------------------------
__global__ __launch_bounds__(512, 1)
void embed_mfma_kernel(const u16* __restrict__ Ahi_g, const u16* __restrict__ Alo_g,
                       const u16* __restrict__ Bhi_g, const u16* __restrict__ Blo_g,
                       const float* __restrict__ be,
                       u16* __restrict__ vhi, u16* __restrict__ vlo, int m_base)
{
    __shared__ char smem[49152];
    const int tid = threadIdx.x;
    const int nb = gridDim.x, q = nb >> 3;
    const int u_ = (blockIdx.x & 7) * q + (blockIdx.x >> 3);   // bijective, nb%8==0
    const int bx = u_ >> 2, by = u_ & 3;
    const int b0 = bx * 64, n0 = by * 128;
    const int w = tid >> 6, l = tid & 63, lm = l & 15, ko4 = l >> 4;
    const int wr = (w >> 2) * 32, wc = (w & 3) * 32;

    const int t8 = tid & 255;
    const char* aS = (const char*)(tid < 256 ? Ahi_g : Alo_g)
                     + (size_t)(b0 + (t8 & 63)) * 4096 + (t8 >> 6) * 16;
    const int bn = tid & 127, bko = tid >> 7;
    const char* bhS = (const char*)Bhi_g + (size_t)(n0 + bn) * 4096 + bko * 16;
    const char* blS = (const char*)Blo_g + (size_t)(n0 + bn) * 4096 + bko * 16;

    auto stage = [&](int s, int buf) {
        char* base = smem + buf * 24576;
        gld16(aS + s * 64, base + (tid >> 8) * 4096 + t8 * 16);
        gld16(bhS + s * 64, base + 8192 + tid * 16);
        gld16(blS + s * 64, base + 16384 + tid * 16);
    };

    f32x4 acc[2][2] = {};
    stage(0, 0);
    for (int kk = 0; kk < 64; ++kk) {
        const int cb = kk & 1;
        if (kk + 1 < 64) {
            stage(kk + 1, cb ^ 1);
            asm volatile("s_waitcnt vmcnt(3)" ::: "memory");
        } else {
            asm volatile("s_waitcnt vmcnt(0)" ::: "memory");
        }
        __builtin_amdgcn_sched_barrier(0);
        __builtin_amdgcn_s_barrier();

        const char* rb = smem + cb * 24576;
        bf16x8 fAh[2], fAl[2], fBh[2], fBl[2];
#pragma unroll
        for (int mt = 0; mt < 2; ++mt) {
            const int idx = ko4 * 64 + wr + mt * 16 + lm;
            fAh[mt] = *(const bf16x8*)(rb + idx * 16);
            fAl[mt] = *(const bf16x8*)(rb + 4096 + idx * 16);
        }
#pragma unroll
        for (int nt = 0; nt < 2; ++nt) {
            const int idx = ko4 * 128 + wc + nt * 16 + lm;
            fBh[nt] = *(const bf16x8*)(rb + 8192 + idx * 16);
            fBl[nt] = *(const bf16x8*)(rb + 16384 + idx * 16);
        }
        asm volatile("s_waitcnt lgkmcnt(0)" ::: "memory");
        __builtin_amdgcn_sched_barrier(0);
        __builtin_amdgcn_s_barrier();
#pragma unroll
        for (int mt = 0; mt < 2; ++mt)
#pragma unroll
            for (int nt = 0; nt < 2; ++nt) {
                acc[mt][nt] = __builtin_amdgcn_mfma_f32_16x16x32_bf16(fAh[mt], fBh[nt], acc[mt][nt], 0, 0, 0);
                acc[mt][nt] = __builtin_amdgcn_mfma_f32_16x16x32_bf16(fAh[mt], fBl[nt], acc[mt][nt], 0, 0, 0);
                acc[mt][nt] = __builtin_amdgcn_mfma_f32_16x16x32_bf16(fAl[mt], fBh[nt], acc[mt][nt], 0, 0, 0);
            }
    }

    __syncthreads();
    float* S = (float*)smem;   // [64][132]
#pragma unroll
    for (int mt = 0; mt < 2; ++mt)
#pragma unroll
        for (int nt = 0; nt < 2; ++nt) {
            const int col = wc + nt * 16 + lm;
#pragma unroll
            for (int r = 0; r < 4; ++r) {
                const int row = wr + mt * 16 + ko4 * 4 + r;
                S[row * 132 + col] = acc[mt][nt][r];
            }
        }
    __syncthreads();

    const int cg = tid & 31, rg = tid >> 5;
    const int p0 = n0 + cg * 4;
    const float4 be4 = *(const float4*)&be[p0];
#pragma unroll
    for (int i = 0; i < 4; ++i) {
        const int m = rg * 4 + i;
        const int R = m_base + b0 + m;
        const int t = R % T_, b = R / T_;
        const float4 g4 = *(const float4*)&S[m * 132 + cg * 4];
        float o[4] = {g4.x + be4.x, g4.y + be4.y, g4.z + be4.z, g4.w + be4.w};
        u16 h[4], lo[4];
#pragma unroll
        for (int j = 0; j < 4; ++j) {
            h[j] = f2bf_rn(o[j]);
            lo[j] = f2bf_rn(o[j] - bf2f(h[j]));
        }
        const size_t off = ((size_t)t * B_ + b) * PROJ_ + p0;
        *(uint2*)&vhi[off] = make_uint2((unsigned)h[0] | ((unsigned)h[1] << 16),
                                        (unsigned)h[2] | ((unsigned)h[3] << 16));
        *(uint2*)&vlo[off] = make_uint2((unsigned)lo[0] | ((unsigned)lo[1] << 16),
                                        (unsigned)lo[2] | ((unsigned)lo[3] << 16));
    }
}

// ---------------------------------------------------------------------------
// LSTM1 step, split-bf16 MFMA. BM=64, BN=128, BK=32, 8 waves (512 thr),
// grid 256, counted-vmcnt dbuf pipeline. Fused BD keep + Pout partials.
// ---------------------------------------------------------------------------
__global__ __launch_bounds__(512, 1)
void lstm_mfma_kernel(const u16* __restrict__ vthi, const u16* __restrict__ vtlo,
                      const u16* __restrict__ hhi,  const u16* __restrict__ hlo,
                      const u16* __restrict__ Whi,  const u16* __restrict__ Wlo,
                      const float* __restrict__ b1,
                      const float* __restrict__ Lv_t,
                      const float* __restrict__ Pin,
                      float* __restrict__ Pout,
                      const float* __restrict__ wsh_v,
                      float* __restrict__ c1, float* __restrict__ h1o,
                      u16* __restrict__ hhio, u16* __restrict__ hloo)
{
    __shared__ char smem[49408];
    float* keepsm = (float*)(smem + 49152);
    const int tid = threadIdx.x;
    const int bid = blockIdx.x;
    const int xcd = bid & 7, slot = bid >> 3;
    const int by  = xcd * 4 + (slot & 3);   // 8 bx-blocks share a W-slice per XCD
    const int bx  = slot >> 2;
    const int b0  = bx * 64, n0 = by * 128;
    const int w = tid >> 6, l = tid & 63, lm = l & 15, ko4 = l >> 4;
    const int wr = (w >> 2) * 32, wc = (w & 3) * 32;

    // keep[b] = (Lv[t][b] + sum_j Pin[j][b] > 0) ? 0 : 1
    if (tid < 64) {
        double s = (double)Lv_t[b0 + tid];
#pragma unroll
        for (int j = 0; j < 32; ++j) s += (double)Pin[j * B_ + b0 + tid];
        keepsm[tid] = (s > 0.0) ? 0.0f : 1.0f;
    }

    const int t8 = tid & 255;
    const int am = t8 & 63, ak = t8 >> 6;
    const int bn = tid & 127, bko = tid >> 7;
    const char* bhS = (const char*)Whi + (size_t)(n0 + bn) * 3072 + bko * 16;
    const char* blS = (const char*)Wlo + (size_t)(n0 + bn) * 3072 + bko * 16;
    const char* aV  = (const char*)(tid < 256 ? vthi : vtlo) + (size_t)(b0 + am) * 1024 + ak * 16;
    const char* aH  = (const char*)(tid < 256 ? hhi  : hlo ) + (size_t)(b0 + am) * 2048 + ak * 16;

    auto stage = [&](int s, int buf) {
        char* base = smem + buf * 24576;
        const char* asrc = (s < 16) ? (aV + s * 64) : (aH + (s - 16) * 64);
        gld16(asrc, base + (tid >> 8) * 4096 + t8 * 16);
        gld16(bhS + s * 64, base + 8192 + tid * 16);
        gld16(blS + s * 64, base + 16384 + tid * 16);
    };

    f32x4 acc[2][2] = {};
    stage(0, 0);
    for (int kk = 0; kk < 48; ++kk) {
        const int cb = kk & 1;
        if (kk + 1 < 48) {
            stage(kk + 1, cb ^ 1);
            asm volatile("s_waitcnt vmcnt(3)" ::: "memory");
        } else {
            asm volatile("s_waitcnt vmcnt(0)" ::: "memory");
        }
        __builtin_amdgcn_sched_barrier(0);
        __builtin_amdgcn_s_barrier();

        const char* rb = smem + cb * 24576;
        bf16x8 fAh[2], fAl[2], fBh[2], fBl[2];
#pragma unroll
        for (int mt = 0; mt < 2; ++mt) {
            const int idx = ko4 * 64 + wr + mt * 16 + lm;
            fAh[mt] = *(const bf16x8*)(rb + idx * 16);
            fAl[mt] = *(const bf16x8*)(rb + 4096 + idx * 16);
        }
#pragma unroll
        for (int nt = 0; nt < 2; ++nt) {
            const int idx = ko4 * 128 + wc + nt * 16 + lm;
            fBh[nt] = *(const bf16x8*)(rb + 8192 + idx * 16);
            fBl[nt] = *(const bf16x8*)(rb + 16384 + idx * 16);
        }
        asm volatile("s_waitcnt lgkmcnt(0)" ::: "memory");
        __builtin_amdgcn_sched_barrier(0);
        __builtin_amdgcn_s_barrier();
#pragma unroll
        for (int mt = 0; mt < 2; ++mt)
#pragma unroll
            for (int nt = 0; nt < 2; ++nt) {
                acc[mt][nt] = __builtin_amdgcn_mfma_f32_16x16x32_bf16(fAh[mt], fBh[nt], acc[mt][nt], 0, 0, 0);
                acc[mt][nt] = __builtin_amdgcn_mfma_f32_16x16x32_bf16(fAh[mt], fBl[nt], acc[mt][nt], 0, 0, 0);
                acc[mt][nt] = __builtin_amdgcn_mfma_f32_16x16x32_bf16(fAl[mt], fBh[nt], acc[mt][nt], 0, 0, 0);
            }
    }

    __syncthreads();
    float* S = (float*)smem;   // [64][132]
#pragma unroll
    for (int mt = 0; mt < 2; ++mt)
#pragma unroll
        for (int nt = 0; nt < 2; ++nt) {
            const int col = wc + nt * 16 + lm;
#pragma unroll
            for (int r = 0; r < 4; ++r) {
                const int row = wr + mt * 16 + ko4 * 4 + r;
                S[row * 132 + col] = acc[mt][nt][r];
            }
        }
    __syncthreads();

    const int h_l = tid & 31, rg = tid >> 5;
    const int hg  = by * 32 + h_l;
    const float bI = b1[hg], bF = b1[HID_ + hg], bG = b1[2 * HID_ + hg], bO = b1[3 * HID_ + hg];
    const float wv = wsh_v[hg];
#pragma unroll
    for (int i = 0; i < 4; ++i) {
        const int m = rg * 4 + i;
        const int b = b0 + m;
        const float4 g4 = *(const float4*)&S[m * 132 + h_l * 4];
        const float i_ = sigmoidf_(g4.x + bI);
        const float f_ = sigmoidf_(g4.y + bF);
        const float g_ = tanhf(g4.z + bG);
        const float o_ = sigmoidf_(g4.w + bO);
        const size_t off = (size_t)b * HID_ + hg;
        float cn = f_ * c1[off] + i_ * g_;
        float hn = o_ * tanhf(cn);
        const float kp = keepsm[m];
        cn *= kp; hn *= kp;
        c1[off] = cn;
        if (h1o) h1o[off] = hn;
        const u16 hb = f2bf_rn(hn);
        hhio[off] = hb;
        hloo[off] = f2bf_rn(hn - bf2f(hb));
        float pr = hn * wv;
        pr += __shfl_xor(pr, 16);
        pr += __shfl_xor(pr, 8);
        pr += __shfl_xor(pr, 4);
        pr += __shfl_xor(pr, 2);
        pr += __shfl_xor(pr, 1);
        if (h_l == 0) Pout[by * B_ + b] = pr;
    }
}

__global__ void b1sum_kernel(const float* __restrict__ bih,
                             const float* __restrict__ bhh,
                             float* __restrict__ b1)
{
    const int i = blockIdx.x * 256 + threadIdx.x;
    if (i < G4_) b1[i] = bih[i] + bhh[i];
}

// ---------------------------------------------------------------------------
extern "C" void kernel_launch(void* const* d_in, const int* in_sizes, int n_in,
                              void* d_out, int out_size, void* d_ws, size_t ws_size,
                              hipStream_t stream)
{
    const float* video = (const float*)d_in[0];
    const float* We    = (const float*)d_in[1];
    const float* be    = (const float*)d_in[2];
    const float* W1_ih = (const float*)d_in[3];
    const float* W1_hh = (const float*)d_in[4];
    const float* b1_ih = (const float*)d_in[5];
    const float* b1_hh = (const float*)d_in[6];
    // d_in[7], d_in[8] (W2_ih, W2_hh): dead — lstm2 never affects the output
    const float* Wsi   = (const float*)d_in[9];
    const float* Wsh   = (const float*)d_in[10];
    const float* bbd   = (const float*)d_in[11];
    const float* vs    = (const float*)d_in[12];
    float* out = (float*)d_out;

    char* p = (char*)d_ws;
    auto alloc = [&](size_t bytes) { char* r = p; p += (bytes + 255) & ~(size_t)255; return r; };
    u16* vhi   = (u16*)alloc((size_t)T_ * B_ * PROJ_ * 2);
    u16* vlo   = (u16*)alloc((size_t)T_ * B_ * PROJ_ * 2);
    u16* Wehi  = (u16*)alloc((size_t)PROJ_ * FRAME_ * 2);
    u16* Welo  = (u16*)alloc((size_t)PROJ_ * FRAME_ * 2);
    float* c1  = (float*)alloc((size_t)B_ * HID_ * 4);
    u16* hhiA  = (u16*)alloc((size_t)B_ * HID_ * 2);
    u16* hhiB  = (u16*)alloc((size_t)B_ * HID_ * 2);
    u16* hloA  = (u16*)alloc((size_t)B_ * HID_ * 2);
    u16* hloB  = (u16*)alloc((size_t)B_ * HID_ * 2);
    double* wsi_vd = (double*)alloc(512 * 8);
    double* ud     = (double*)alloc(2048 * 8);
    double* ccd    = (double*)alloc(256);
    float* wsh_v = (float*)alloc(1024 * 4);
    float* Lv    = (float*)alloc((size_t)T_ * B_ * 4);
    float* PA    = (float*)alloc(32 * B_ * 4);
    float* PB    = (float*)alloc(32 * B_ * 4);
    float* b1    = (float*)alloc(G4_ * 4);
    u16* Whi   = (u16*)alloc((size_t)G4_ * 1536 * 2);   // 12,582,912 B
    u16* Wlo   = (u16*)alloc((size_t)G4_ * 1536 * 2);
    // video chunk hi/lo planes ALIAS the Whi/Wlo region (exactly 12,582,912 B
    // each at 8 chunks of 3072 rows); wsplit runs after the embed phase.
    u16* vidhi = Whi;
    u16* vidlo = Wlo;

    hipMemsetAsync(c1,   0, (size_t)B_ * HID_ * 4, stream);
    hipMemsetAsync(hhiA, 0, (size_t)B_ * HID_ * 2, stream);
    hipMemsetAsync(hloA, 0, (size_t)B_ * HID_ * 2, stream);
    hipMemsetAsync(PA,   0, 32 * B_ * 4, stream);

    b1sum_kernel<<<16, 256, 0, stream>>>(b1_ih, b1_hh, b1);
    wvec_kernel<<<6, 256, 0, stream>>>(Wsi, Wsh, vs, wsi_vd, wsh_v);
    cc_kernel<<<1, 256, 0, stream>>>(be, wsi_vd, vs, bbd, ccd);
    u_kernel<<<8, 256, 0, stream>>>(We, wsi_vd, ud);
    lv_kernel<<<6144, 256, 0, stream>>>(video, ud, ccd, Lv);
    split_kernel<<<1024, 256, 0, stream>>>(We, Wehi, Welo, PROJ_ * FRAME_ / 4);

    // embed in 8 chunks of 3072 rows
    const int ROWS_C = 3072;
    for (int c = 0; c < 8; ++c) {
        const float* vsrc = video + (size_t)c * ROWS_C * FRAME_;
        split_kernel<<<ROWS_C * FRAME_ / 4 / 256, 256, 0, stream>>>(vsrc, vidhi, vidlo,
                                                                    ROWS_C * FRAME_ / 4);
        embed_mfma_kernel<<<192, 512, 0, stream>>>(vidhi, vidlo, Wehi, Welo, be,
                                                   vhi, vlo, c * ROWS_C);
    }

    wsplit_kernel<<<6144, 256, 0, stream>>>(W1_ih, W1_hh, Whi, Wlo);

    u16* hhi_in = hhiA; u16* hhi_out = hhiB;
    u16* hlo_in = hloA; u16* hlo_out = hloB;
    float* Pin = PA; float* Pout = PB;

    for (int t = 0; t < T_; ++t) {
        const u16* vthi = vhi + (size_t)t * B_ * PROJ_;
        const u16* vtlo = vlo + (size_t)t * B_ * PROJ_;
        float* ho = (t == T_ - 1) ? out : nullptr;
        lstm_mfma_kernel<<<256, 512, 0, stream>>>(vthi, vtlo, hhi_in, hlo_in,
                                                  Whi, Wlo, b1,
                                                  Lv + t * B_, Pin, Pout, wsh_v,
                                                  c1, ho, hhi_out, hlo_out);
        { u16* tmp = hhi_in; hhi_in = hhi_out; hhi_out = tmp; }
        { u16* tmp = hlo_in; hlo_in = hlo_out; hlo_out = tmp; }
        { float* tmp = Pin; Pin = Pout; Pout = tmp; }
    }
}

// Round 5
// 1698.624 us; speedup vs baseline: 4.8979x; 1.6731x over previous
//
#include <hip/hip_runtime.h>

#define B_     512
#define T_     48
#define FRAME_ 2048
#define PROJ_  512
#define MID_   128
#define HID_   1024
#define G4_    4096

typedef unsigned short u16;
typedef __bf16 bf16x8 __attribute__((ext_vector_type(8)));
typedef float  f32x4  __attribute__((ext_vector_type(4)));

__device__ __forceinline__ float sigmoidf_(float x) {
    return 1.0f / (1.0f + expf(-x));
}
__device__ __forceinline__ u16 f2bf_rn(float f) {
    unsigned int u = __float_as_uint(f);
    u += 0x7fffu + ((u >> 16) & 1u);
    return (u16)(u >> 16);
}
__device__ __forceinline__ float bf2f(u16 s) {
    return __uint_as_float(((unsigned int)s) << 16);
}
__device__ __forceinline__ void gld16(const void* g, void* l) {
    __builtin_amdgcn_global_load_lds((const __attribute__((address_space(1))) void*)g,
                                     (__attribute__((address_space(3))) void*)l, 16, 0, 0);
}
__device__ __forceinline__ uint4 pack8(const u16* h) {
    return make_uint4((unsigned)h[0] | ((unsigned)h[1] << 16),
                      (unsigned)h[2] | ((unsigned)h[3] << 16),
                      (unsigned)h[4] | ((unsigned)h[5] << 16),
                      (unsigned)h[6] | ((unsigned)h[7] << 16));
}

// ---------------------------------------------------------------------------
// BD linearization precompute (exact fp64 path)
// ---------------------------------------------------------------------------
__global__ void wvec_kernel(const float* __restrict__ Wsi, const float* __restrict__ Wsh,
                            const float* __restrict__ vs,
                            double* __restrict__ wsi_vd, float* __restrict__ wsh_v)
{
    const int gid = blockIdx.x * 256 + threadIdx.x;
    if (gid < 512) {
        double s = 0.0;
        for (int mi = 0; mi < MID_; ++mi)
            s += (double)vs[mi] * (double)Wsi[(size_t)mi * PROJ_ + gid];
        wsi_vd[gid] = s;
    } else if (gid < 1536) {
        const int k = gid - 512;
        double s = 0.0;
        for (int mi = 0; mi < MID_; ++mi)
            s += (double)vs[mi] * (double)Wsh[(size_t)mi * HID_ + k];
        wsh_v[k] = (float)s;
    }
}

__global__ void cc_kernel(const float* __restrict__ be, const double* __restrict__ wsi_vd,
                          const float* __restrict__ vs, const float* __restrict__ bbd,
                          double* __restrict__ cc)
{
    __shared__ double red[256];
    const int tid = threadIdx.x;
    double s = 0.0;
    for (int p = tid; p < PROJ_; p += 256) s += (double)be[p] * wsi_vd[p];
    red[tid] = s;
    __syncthreads();
    for (int st = 128; st > 0; st >>= 1) {
        if (tid < st) red[tid] += red[tid + st];
        __syncthreads();
    }
    if (tid == 0) {
        double b = 0.0;
        for (int mi = 0; mi < MID_; ++mi) b += (double)vs[mi] * (double)bbd[mi];
        cc[0] = red[0] + b;
    }
}

__global__ void u_kernel(const float* __restrict__ We, const double* __restrict__ wsi_vd,
                         double* __restrict__ u)
{
    const int f = blockIdx.x * 256 + threadIdx.x;   // 2048
    double s = 0.0;
    for (int p = 0; p < PROJ_; ++p)
        s += wsi_vd[p] * (double)We[(size_t)p * FRAME_ + f];
    u[f] = s;
}

// ---------------------------------------------------------------------------
// vidpack: video fp32 -> packed bf16 hi/lo planes  vid'[kk][ko][row]
//   (granule = 8 k of one row at [( kk*4+ko )*24576 + row]*16B)
// Fused: Lv[t][b] = video[row]·u + cc   (fp64, per-block reduction)
// grid 1536 (16 rows/block), block 256: r = tid&15, kq = tid>>4 (128 k each)
// ---------------------------------------------------------------------------
__global__ __launch_bounds__(256)
void vidpack_kernel(const float* __restrict__ video, const double* __restrict__ u,
                    const double* __restrict__ cc,
                    u16* __restrict__ phi, u16* __restrict__ plo,
                    float* __restrict__ Lv)
{
    __shared__ double red[16][17];
    const int tid = threadIdx.x;
    const int r   = tid & 15, kq = tid >> 4;
    const int row = blockIdx.x * 16 + r;
    const float* vr = video + (size_t)row * FRAME_;
    double s = 0.0;
#pragma unroll
    for (int j = 0; j < 16; ++j) {
        const int k0 = kq * 128 + j * 8;
        const float4 a = *(const float4*)&vr[k0];
        const float4 b = *(const float4*)&vr[k0 + 4];
        const float f[8] = {a.x, a.y, a.z, a.w, b.x, b.y, b.z, b.w};
        s += (double)f[0]*u[k0+0] + (double)f[1]*u[k0+1] + (double)f[2]*u[k0+2]
           + (double)f[3]*u[k0+3] + (double)f[4]*u[k0+4] + (double)f[5]*u[k0+5]
           + (double)f[6]*u[k0+6] + (double)f[7]*u[k0+7];
        u16 h[8], l[8];
#pragma unroll
        for (int e = 0; e < 8; ++e) {
            h[e] = f2bf_rn(f[e]);
            l[e] = f2bf_rn(f[e] - bf2f(h[e]));
        }
        const int g = kq * 16 + j;     // global k-octet 0..255 (= kk*4+ko)
        const size_t off = ((size_t)g * 24576 + row) * 16;
        *(uint4*)((char*)phi + off) = pack8(h);
        *(uint4*)((char*)plo + off) = pack8(l);
    }
    red[r][kq] = s;
    __syncthreads();
    if (tid < 16) {
        double t = 0.0;
#pragma unroll
        for (int q = 0; q < 16; ++q) t += red[tid][q];
        const int rw = blockIdx.x * 16 + tid;
        Lv[(rw % T_) * B_ + rw / T_] = (float)(t + cc[0]);
    }
}

// ---------------------------------------------------------------------------
// wepack: We -> packed planes  We'[by][kk][ko*128+n]  (n = p local)
// grid (64 kk, 4 by), block 256, 2 granules/thread/plane
// ---------------------------------------------------------------------------
__global__ void wepack_kernel(const float* __restrict__ We,
                              u16* __restrict__ phi, u16* __restrict__ plo)
{
    const int kk = blockIdx.x, by = blockIdx.y, tid = threadIdx.x;
#pragma unroll
    for (int pass = 0; pass < 2; ++pass) {
        const int g = tid + pass * 256;          // 0..511
        const int ko = g >> 7, n = g & 127;
        const int p = by * 128 + n;
        const int k = kk * 32 + ko * 8;
        const float4 a = *(const float4*)&We[(size_t)p * FRAME_ + k];
        const float4 b = *(const float4*)&We[(size_t)p * FRAME_ + k + 4];
        const float f[8] = {a.x, a.y, a.z, a.w, b.x, b.y, b.z, b.w};
        u16 h[8], l[8];
#pragma unroll
        for (int e = 0; e < 8; ++e) {
            h[e] = f2bf_rn(f[e]);
            l[e] = f2bf_rn(f[e] - bf2f(h[e]));
        }
        const size_t off = (((size_t)by * 64 + kk) * 512 + g) * 16;
        *(uint4*)((char*)phi + off) = pack8(h);
        *(uint4*)((char*)plo + off) = pack8(l);
    }
}

// ---------------------------------------------------------------------------
// wpack: W1 (gate-interleaved rows, K=[ih|hh]) -> W'[by][kk][ko*128+n]
// grid (48 kk, 32 by), block 256, 2 granules/thread/plane
// ---------------------------------------------------------------------------
__global__ void wpack_kernel(const float* __restrict__ Wih, const float* __restrict__ Whh,
                             u16* __restrict__ phi, u16* __restrict__ plo)
{
    const int kk = blockIdx.x, by = blockIdx.y, tid = threadIdx.x;
#pragma unroll
    for (int pass = 0; pass < 2; ++pass) {
        const int g = tid + pass * 256;
        const int ko = g >> 7, n = g & 127;
        const int gate = n & 3, hl = n >> 2;
        const int srow = gate * HID_ + by * 32 + hl;
        const int k = kk * 32 + ko * 8;
        float4 a, b;
        if (k < 512) {
            a = *(const float4*)&Wih[(size_t)srow * PROJ_ + k];
            b = *(const float4*)&Wih[(size_t)srow * PROJ_ + k + 4];
        } else {
            a = *(const float4*)&Whh[(size_t)srow * HID_ + (k - 512)];
            b = *(const float4*)&Whh[(size_t)srow * HID_ + (k - 508)];
        }
        const float f[8] = {a.x, a.y, a.z, a.w, b.x, b.y, b.z, b.w};
        u16 h[8], l[8];
#pragma unroll
        for (int e = 0; e < 8; ++e) {
            h[e] = f2bf_rn(f[e]);
            l[e] = f2bf_rn(f[e] - bf2f(h[e]));
        }
        const size_t off = (((size_t)by * 48 + kk) * 512 + g) * 16;
        *(uint4*)((char*)phi + off) = pack8(h);
        *(uint4*)((char*)plo + off) = pack8(l);
    }
}

// ---------------------------------------------------------------------------
// embed GEMM: v = video @ We^T + be, split-bf16 MFMA, packed-coalesced staging.
// BM=64, BN=128, BK=32, 8 waves, 3-buf vmcnt(6) pipeline, NK=64.
// Epilogue writes vt'[t][kk][ko*... packed granules (hi/lo).
// ---------------------------------------------------------------------------
__global__ __launch_bounds__(512, 1)
void embed_mfma_kernel(const u16* __restrict__ Ahi_g, const u16* __restrict__ Alo_g,
                       const u16* __restrict__ Bhi_g, const u16* __restrict__ Blo_g,
                       const float* __restrict__ be,
                       u16* __restrict__ vphi, u16* __restrict__ vplo)
{
    __shared__ char smem[73728];
    const int tid = threadIdx.x;
    const int u_ = (blockIdx.x & 7) * 192 + (blockIdx.x >> 3);   // 1536 blocks
    const int by = u_ / 384, bx = u_ % 384;                       // by-grouped per XCD
    const int n0 = by * 128;
    const int w = tid >> 6, l = tid & 63, lm = l & 15, ko4 = l >> 4;
    const int wr = (w >> 2) * 32, wc = (w & 3) * 32;
    const int t8 = tid & 255;
    const int koA = t8 >> 6, am = t8 & 63;

    const char* aV = (const char*)(tid < 256 ? Ahi_g : Alo_g)
                     + (size_t)koA * 393216 + ((size_t)bx * 64 + am) * 16;
    const char* bh = (const char*)Bhi_g + (size_t)by * 524288 + tid * 16;
    const char* bl = (const char*)Blo_g + (size_t)by * 524288 + tid * 16;

    auto stage = [&](int s, int buf) {
        char* base = smem + buf * 24576;
        gld16(aV + (size_t)s * 1572864, base + (tid >> 8) * 4096 + t8 * 16);
        gld16(bh + (size_t)s * 8192, base + 8192 + tid * 16);
        gld16(bl + (size_t)s * 8192, base + 16384 + tid * 16);
    };

    f32x4 acc[2][2] = {};
    stage(0, 0);
    stage(1, 1);
    for (int kk = 0; kk < 64; ++kk) {
        const int cb = kk % 3;
        if (kk + 2 < 64) {
            stage(kk + 2, (kk + 2) % 3);
            asm volatile("s_waitcnt vmcnt(6)" ::: "memory");
        } else if (kk + 1 < 64) {
            asm volatile("s_waitcnt vmcnt(3)" ::: "memory");
        } else {
            asm volatile("s_waitcnt vmcnt(0)" ::: "memory");
        }
        __builtin_amdgcn_sched_barrier(0);
        __builtin_amdgcn_s_barrier();

        const char* rb = smem + cb * 24576;
        bf16x8 fAh[2], fAl[2], fBh[2], fBl[2];
#pragma unroll
        for (int mt = 0; mt < 2; ++mt) {
            const int idx = ko4 * 64 + wr + mt * 16 + lm;
            fAh[mt] = *(const bf16x8*)(rb + idx * 16);
            fAl[mt] = *(const bf16x8*)(rb + 4096 + idx * 16);
        }
#pragma unroll
        for (int nt = 0; nt < 2; ++nt) {
            const int idx = ko4 * 128 + wc + nt * 16 + lm;
            fBh[nt] = *(const bf16x8*)(rb + 8192 + idx * 16);
            fBl[nt] = *(const bf16x8*)(rb + 16384 + idx * 16);
        }
        asm volatile("s_waitcnt lgkmcnt(0)" ::: "memory");
        __builtin_amdgcn_sched_barrier(0);
        __builtin_amdgcn_s_barrier();
        __builtin_amdgcn_s_setprio(1);
#pragma unroll
        for (int mt = 0; mt < 2; ++mt)
#pragma unroll
            for (int nt = 0; nt < 2; ++nt) {
                acc[mt][nt] = __builtin_amdgcn_mfma_f32_16x16x32_bf16(fAh[mt], fBh[nt], acc[mt][nt], 0, 0, 0);
                acc[mt][nt] = __builtin_amdgcn_mfma_f32_16x16x32_bf16(fAh[mt], fBl[nt], acc[mt][nt], 0, 0, 0);
                acc[mt][nt] = __builtin_amdgcn_mfma_f32_16x16x32_bf16(fAl[mt], fBh[nt], acc[mt][nt], 0, 0, 0);
            }
        __builtin_amdgcn_s_setprio(0);
    }

    __syncthreads();
    float* S = (float*)smem;   // [64][132]
#pragma unroll
    for (int mt = 0; mt < 2; ++mt)
#pragma unroll
        for (int nt = 0; nt < 2; ++nt) {
            const int col = wc + nt * 16 + lm;
#pragma unroll
            for (int r = 0; r < 4; ++r) {
                const int row = wr + mt * 16 + ko4 * 4 + r;
                S[row * 132 + col] = acc[mt][nt][r];
            }
        }
    __syncthreads();

#pragma unroll
    for (int pass = 0; pass < 2; ++pass) {
        const int pidx = tid + pass * 512;
        const int m = pidx >> 4, gr = pidx & 15;
        const int p0 = n0 + gr * 8;
        const float4 s0 = *(const float4*)&S[m * 132 + gr * 8];
        const float4 s1 = *(const float4*)&S[m * 132 + gr * 8 + 4];
        const float4 e0 = *(const float4*)&be[p0];
        const float4 e1 = *(const float4*)&be[p0 + 4];
        const float o[8] = {s0.x + e0.x, s0.y + e0.y, s0.z + e0.z, s0.w + e0.w,
                            s1.x + e1.x, s1.y + e1.y, s1.z + e1.z, s1.w + e1.w};
        u16 h[8], lo[8];
#pragma unroll
        for (int e = 0; e < 8; ++e) {
            h[e] = f2bf_rn(o[e]);
            lo[e] = f2bf_rn(o[e] - bf2f(h[e]));
        }
        const int R = bx * 64 + m;
        const int t = R % T_, b = R / T_;
        const size_t off = (size_t)t * 524288 + (((size_t)(p0 >> 3)) * 512 + b) * 16;
        *(uint4*)((char*)vphi + off) = pack8(h);
        *(uint4*)((char*)vplo + off) = pack8(lo);
    }
}

// ---------------------------------------------------------------------------
// LSTM1 step: packed-coalesced staging, 3-buf vmcnt(6) pipeline, NK=48.
// A: vt'[t] (kk<16) then h' (kk>=16); B: W'. Fused keep + cell + Pout + h'-out.
// ---------------------------------------------------------------------------
__global__ __launch_bounds__(512, 1)
void lstm_mfma_kernel(const u16* __restrict__ vthi, const u16* __restrict__ vtlo,
                      const u16* __restrict__ hhi,  const u16* __restrict__ hlo,
                      const u16* __restrict__ Whi,  const u16* __restrict__ Wlo,
                      const float* __restrict__ b1,
                      const float* __restrict__ Lv_t,
                      const float* __restrict__ Pin,
                      float* __restrict__ Pout,
                      const float* __restrict__ wsh_v,
                      float* __restrict__ c1, float* __restrict__ h1o,
                      u16* __restrict__ hhio, u16* __restrict__ hloo)
{
    __shared__ char smem[73984];
    float* keepsm = (float*)(smem + 73728);
    const int tid = threadIdx.x;
    const int bid = blockIdx.x;
    const int xcd = bid & 7, slot = bid >> 3;
    const int by  = xcd * 4 + (slot & 3);
    const int bx  = slot >> 2;
    const int b0  = bx * 64;
    const int w = tid >> 6, l = tid & 63, lm = l & 15, ko4 = l >> 4;
    const int wr = (w >> 2) * 32, wc = (w & 3) * 32;
    const int t8 = tid & 255;
    const int koA = t8 >> 6, am = t8 & 63;

    const char* aV = (const char*)(tid < 256 ? vthi : vtlo)
                     + koA * 8192 + (b0 + am) * 16;
    const char* aH = (const char*)(tid < 256 ? hhi : hlo)
                     + koA * 8192 + (b0 + am) * 16;
    const char* bh = (const char*)Whi + (size_t)by * 393216 + tid * 16;
    const char* bl = (const char*)Wlo + (size_t)by * 393216 + tid * 16;

    auto stage = [&](int s, int buf) {
        char* base = smem + buf * 24576;
        const char* asrc = (s < 16) ? aV + s * 32768 : aH + (s - 16) * 32768;
        gld16(asrc, base + (tid >> 8) * 4096 + t8 * 16);
        gld16(bh + s * 8192, base + 8192 + tid * 16);
        gld16(bl + s * 8192, base + 16384 + tid * 16);
    };

    f32x4 acc[2][2] = {};
    stage(0, 0);
    stage(1, 1);

    if (tid < 64) {
        double s = (double)Lv_t[b0 + tid];
#pragma unroll
        for (int j = 0; j < 32; ++j) s += (double)Pin[j * B_ + b0 + tid];
        keepsm[tid] = (s > 0.0) ? 0.0f : 1.0f;
    }

    for (int kk = 0; kk < 48; ++kk) {
        const int cb = kk % 3;
        if (kk + 2 < 48) {
            stage(kk + 2, (kk + 2) % 3);
            asm volatile("s_waitcnt vmcnt(6)" ::: "memory");
        } else if (kk + 1 < 48) {
            asm volatile("s_waitcnt vmcnt(3)" ::: "memory");
        } else {
            asm volatile("s_waitcnt vmcnt(0)" ::: "memory");
        }
        __builtin_amdgcn_sched_barrier(0);
        __builtin_amdgcn_s_barrier();

        const char* rb = smem + cb * 24576;
        bf16x8 fAh[2], fAl[2], fBh[2], fBl[2];
#pragma unroll
        for (int mt = 0; mt < 2; ++mt) {
            const int idx = ko4 * 64 + wr + mt * 16 + lm;
            fAh[mt] = *(const bf16x8*)(rb + idx * 16);
            fAl[mt] = *(const bf16x8*)(rb + 4096 + idx * 16);
        }
#pragma unroll
        for (int nt = 0; nt < 2; ++nt) {
            const int idx = ko4 * 128 + wc + nt * 16 + lm;
            fBh[nt] = *(const bf16x8*)(rb + 8192 + idx * 16);
            fBl[nt] = *(const bf16x8*)(rb + 16384 + idx * 16);
        }
        asm volatile("s_waitcnt lgkmcnt(0)" ::: "memory");
        __builtin_amdgcn_sched_barrier(0);
        __builtin_amdgcn_s_barrier();
        __builtin_amdgcn_s_setprio(1);
#pragma unroll
        for (int mt = 0; mt < 2; ++mt)
#pragma unroll
            for (int nt = 0; nt < 2; ++nt) {
                acc[mt][nt] = __builtin_amdgcn_mfma_f32_16x16x32_bf16(fAh[mt], fBh[nt], acc[mt][nt], 0, 0, 0);
                acc[mt][nt] = __builtin_amdgcn_mfma_f32_16x16x32_bf16(fAh[mt], fBl[nt], acc[mt][nt], 0, 0, 0);
                acc[mt][nt] = __builtin_amdgcn_mfma_f32_16x16x32_bf16(fAl[mt], fBh[nt], acc[mt][nt], 0, 0, 0);
            }
        __builtin_amdgcn_s_setprio(0);
    }

    __syncthreads();
    float* S = (float*)smem;   // [64][132]
#pragma unroll
    for (int mt = 0; mt < 2; ++mt)
#pragma unroll
        for (int nt = 0; nt < 2; ++nt) {
            const int col = wc + nt * 16 + lm;
#pragma unroll
            for (int r = 0; r < 4; ++r) {
                const int row = wr + mt * 16 + ko4 * 4 + r;
                S[row * 132 + col] = acc[mt][nt][r];
            }
        }
    __syncthreads();

    const int h_l = tid & 31, rg = tid >> 5;
    const int hg  = by * 32 + h_l;
    const float bI = b1[hg], bF = b1[HID_ + hg], bG = b1[2 * HID_ + hg], bO = b1[3 * HID_ + hg];
    const float wv = wsh_v[hg];
    // packed h' dest: [kkh=by][ko=h_l>>3][m=b], byte (h_l&7)*2 within granule
    const size_t hgbase = (((size_t)by * 4 + (h_l >> 3)) * 512) * 16 + (h_l & 7) * 2;
#pragma unroll
    for (int i = 0; i < 4; ++i) {
        const int m = rg * 4 + i;
        const int b = b0 + m;
        const float4 g4 = *(const float4*)&S[m * 132 + h_l * 4];
        const float i_ = sigmoidf_(g4.x + bI);
        const float f_ = sigmoidf_(g4.y + bF);
        const float g_ = tanhf(g4.z + bG);
        const float o_ = sigmoidf_(g4.w + bO);
        const size_t off = (size_t)b * HID_ + hg;
        float cn = f_ * c1[off] + i_ * g_;
        float hn = o_ * tanhf(cn);
        const float kp = keepsm[m];
        cn *= kp; hn *= kp;
        c1[off] = cn;
        if (h1o) h1o[off] = hn;
        const u16 hb = f2bf_rn(hn);
        const size_t hoff = hgbase + (size_t)b * 16;
        *(u16*)((char*)hhio + hoff) = hb;
        *(u16*)((char*)hloo + hoff) = f2bf_rn(hn - bf2f(hb));
        float pr = hn * wv;
        pr += __shfl_xor(pr, 16);
        pr += __shfl_xor(pr, 8);
        pr += __shfl_xor(pr, 4);
        pr += __shfl_xor(pr, 2);
        pr += __shfl_xor(pr, 1);
        if (h_l == 0) Pout[by * B_ + b] = pr;
    }
}

__global__ void b1sum_kernel(const float* __restrict__ bih,
                             const float* __restrict__ bhh,
                             float* __restrict__ b1)
{
    const int i = blockIdx.x * 256 + threadIdx.x;
    if (i < G4_) b1[i] = bih[i] + bhh[i];
}

// ---------------------------------------------------------------------------
extern "C" void kernel_launch(void* const* d_in, const int* in_sizes, int n_in,
                              void* d_out, int out_size, void* d_ws, size_t ws_size,
                              hipStream_t stream)
{
    const float* video = (const float*)d_in[0];
    const float* We    = (const float*)d_in[1];
    const float* be    = (const float*)d_in[2];
    const float* W1_ih = (const float*)d_in[3];
    const float* W1_hh = (const float*)d_in[4];
    const float* b1_ih = (const float*)d_in[5];
    const float* b1_hh = (const float*)d_in[6];
    // d_in[7], d_in[8] (W2_ih, W2_hh): dead — lstm2 never affects the output
    const float* Wsi   = (const float*)d_in[9];
    const float* Wsh   = (const float*)d_in[10];
    const float* bbd   = (const float*)d_in[11];
    const float* vs    = (const float*)d_in[12];
    float* out = (float*)d_out;

    char* p = (char*)d_ws;
    auto alloc = [&](size_t bytes) { char* r = p; p += (bytes + 255) & ~(size_t)255; return r; };
    u16* vidhi = (u16*)alloc((size_t)24576 * FRAME_ * 2);   // 96 MB
    u16* vidlo = (u16*)alloc((size_t)24576 * FRAME_ * 2);   // 96 MB
    u16* vphi  = (u16*)alloc((size_t)T_ * B_ * PROJ_ * 2);  // 24 MB
    u16* vplo  = (u16*)alloc((size_t)T_ * B_ * PROJ_ * 2);
    u16* Wehi  = (u16*)alloc((size_t)PROJ_ * FRAME_ * 2);   // 2 MB
    u16* Welo  = (u16*)alloc((size_t)PROJ_ * FRAME_ * 2);
    u16* Whi   = (u16*)alloc((size_t)G4_ * 1536 * 2);       // 12.6 MB
    u16* Wlo   = (u16*)alloc((size_t)G4_ * 1536 * 2);
    float* c1  = (float*)alloc((size_t)B_ * HID_ * 4);
    u16* hhiA  = (u16*)alloc((size_t)B_ * HID_ * 2);
    u16* hhiB  = (u16*)alloc((size_t)B_ * HID_ * 2);
    u16* hloA  = (u16*)alloc((size_t)B_ * HID_ * 2);
    u16* hloB  = (u16*)alloc((size_t)B_ * HID_ * 2);
    double* wsi_vd = (double*)alloc(512 * 8);
    double* ud     = (double*)alloc(2048 * 8);
    double* ccd    = (double*)alloc(256);
    float* wsh_v = (float*)alloc(1024 * 4);
    float* Lv    = (float*)alloc((size_t)T_ * B_ * 4);
    float* PA    = (float*)alloc(32 * B_ * 4);
    float* PB    = (float*)alloc(32 * B_ * 4);
    float* b1    = (float*)alloc(G4_ * 4);

    hipMemsetAsync(c1,   0, (size_t)B_ * HID_ * 4, stream);
    hipMemsetAsync(hhiA, 0, (size_t)B_ * HID_ * 2, stream);
    hipMemsetAsync(hloA, 0, (size_t)B_ * HID_ * 2, stream);
    hipMemsetAsync(PA,   0, 32 * B_ * 4, stream);

    b1sum_kernel<<<16, 256, 0, stream>>>(b1_ih, b1_hh, b1);
    wvec_kernel<<<6, 256, 0, stream>>>(Wsi, Wsh, vs, wsi_vd, wsh_v);
    cc_kernel<<<1, 256, 0, stream>>>(be, wsi_vd, vs, bbd, ccd);
    u_kernel<<<8, 256, 0, stream>>>(We, wsi_vd, ud);
    wepack_kernel<<<dim3(64, 4), 256, 0, stream>>>(We, Wehi, Welo);
    wpack_kernel<<<dim3(48, 32), 256, 0, stream>>>(W1_ih, W1_hh, Whi, Wlo);
    vidpack_kernel<<<1536, 256, 0, stream>>>(video, ud, ccd, vidhi, vidlo, Lv);
    embed_mfma_kernel<<<1536, 512, 0, stream>>>(vidhi, vidlo, Wehi, Welo, be, vphi, vplo);

    u16* hhi_in = hhiA; u16* hhi_out = hhiB;
    u16* hlo_in = hloA; u16* hlo_out = hloB;
    float* Pin = PA; float* Pout = PB;

    for (int t = 0; t < T_; ++t) {
        const u16* vthi = vphi + (size_t)t * 262144;
        const u16* vtlo = vplo + (size_t)t * 262144;
        float* ho = (t == T_ - 1) ? out : nullptr;
        lstm_mfma_kernel<<<256, 512, 0, stream>>>(vthi, vtlo, hhi_in, hlo_in,
                                                  Whi, Wlo, b1,
                                                  Lv + t * B_, Pin, Pout, wsh_v,
                                                  c1, ho, hhi_out, hlo_out);
        { u16* tmp = hhi_in; hhi_in = hhi_out; hhi_out = tmp; }
        { u16* tmp = hlo_in; hlo_in = hlo_out; hlo_out = tmp; }
        { float* tmp = Pin; Pin = Pout; Pout = tmp; }
    }
}

// Round 6
// 1664.199 us; speedup vs baseline: 4.9992x; 1.0207x over previous
//
#include <hip/hip_runtime.h>

#define B_     512
#define T_     48
#define FRAME_ 2048
#define PROJ_  512
#define MID_   128
#define HID_   1024
#define G4_    4096

typedef unsigned short u16;
typedef __bf16 bf16x8 __attribute__((ext_vector_type(8)));
typedef float  f32x4  __attribute__((ext_vector_type(4)));

__device__ __forceinline__ float sigmoidf_(float x) {
    return 1.0f / (1.0f + expf(-x));
}
__device__ __forceinline__ u16 f2bf_rn(float f) {
    unsigned int u = __float_as_uint(f);
    u += 0x7fffu + ((u >> 16) & 1u);
    return (u16)(u >> 16);
}
__device__ __forceinline__ float bf2f(u16 s) {
    return __uint_as_float(((unsigned int)s) << 16);
}
__device__ __forceinline__ void gld16(const void* g, void* l) {
    __builtin_amdgcn_global_load_lds((const __attribute__((address_space(1))) void*)g,
                                     (__attribute__((address_space(3))) void*)l, 16, 0, 0);
}
__device__ __forceinline__ uint4 pack8(const u16* h) {
    return make_uint4((unsigned)h[0] | ((unsigned)h[1] << 16),
                      (unsigned)h[2] | ((unsigned)h[3] << 16),
                      (unsigned)h[4] | ((unsigned)h[5] << 16),
                      (unsigned)h[6] | ((unsigned)h[7] << 16));
}

// ---------------------------------------------------------------------------
// BD linearization precompute (exact fp64 path)
// ---------------------------------------------------------------------------
__global__ void wvec_kernel(const float* __restrict__ Wsi, const float* __restrict__ Wsh,
                            const float* __restrict__ vs,
                            double* __restrict__ wsi_vd, float* __restrict__ wsh_v)
{
    const int gid = blockIdx.x * 256 + threadIdx.x;
    if (gid < 512) {
        double s = 0.0;
        for (int mi = 0; mi < MID_; ++mi)
            s += (double)vs[mi] * (double)Wsi[(size_t)mi * PROJ_ + gid];
        wsi_vd[gid] = s;
    } else if (gid < 1536) {
        const int k = gid - 512;
        double s = 0.0;
        for (int mi = 0; mi < MID_; ++mi)
            s += (double)vs[mi] * (double)Wsh[(size_t)mi * HID_ + k];
        wsh_v[k] = (float)s;
    }
}

__global__ void cc_kernel(const float* __restrict__ be, const double* __restrict__ wsi_vd,
                          const float* __restrict__ vs, const float* __restrict__ bbd,
                          double* __restrict__ cc)
{
    __shared__ double red[256];
    const int tid = threadIdx.x;
    double s = 0.0;
    for (int p = tid; p < PROJ_; p += 256) s += (double)be[p] * wsi_vd[p];
    red[tid] = s;
    __syncthreads();
    for (int st = 128; st > 0; st >>= 1) {
        if (tid < st) red[tid] += red[tid + st];
        __syncthreads();
    }
    if (tid == 0) {
        double b = 0.0;
        for (int mi = 0; mi < MID_; ++mi) b += (double)vs[mi] * (double)bbd[mi];
        cc[0] = red[0] + b;
    }
}

__global__ void u_kernel(const float* __restrict__ We, const double* __restrict__ wsi_vd,
                         double* __restrict__ u)
{
    const int f = blockIdx.x * 256 + threadIdx.x;   // 2048
    double s = 0.0;
    for (int p = 0; p < PROJ_; ++p)
        s += wsi_vd[p] * (double)We[(size_t)p * FRAME_ + f];
    u[f] = s;
}

// ---------------------------------------------------------------------------
// vidpack: video fp32 -> packed bf16 hi/lo planes  vid'[g][row], g=k-octet
// Fused: Lv[t][b] = video[row]·u + cc   (fp64)
// ---------------------------------------------------------------------------
__global__ __launch_bounds__(256)
void vidpack_kernel(const float* __restrict__ video, const double* __restrict__ u,
                    const double* __restrict__ cc,
                    u16* __restrict__ phi, u16* __restrict__ plo,
                    float* __restrict__ Lv)
{
    __shared__ double red[16][17];
    const int tid = threadIdx.x;
    const int r   = tid & 15, kq = tid >> 4;
    const int row = blockIdx.x * 16 + r;
    const float* vr = video + (size_t)row * FRAME_;
    double s = 0.0;
#pragma unroll
    for (int j = 0; j < 16; ++j) {
        const int k0 = kq * 128 + j * 8;
        const float4 a = *(const float4*)&vr[k0];
        const float4 b = *(const float4*)&vr[k0 + 4];
        const float f[8] = {a.x, a.y, a.z, a.w, b.x, b.y, b.z, b.w};
        s += (double)f[0]*u[k0+0] + (double)f[1]*u[k0+1] + (double)f[2]*u[k0+2]
           + (double)f[3]*u[k0+3] + (double)f[4]*u[k0+4] + (double)f[5]*u[k0+5]
           + (double)f[6]*u[k0+6] + (double)f[7]*u[k0+7];
        u16 h[8], l[8];
#pragma unroll
        for (int e = 0; e < 8; ++e) {
            h[e] = f2bf_rn(f[e]);
            l[e] = f2bf_rn(f[e] - bf2f(h[e]));
        }
        const int g = kq * 16 + j;
        const size_t off = ((size_t)g * 24576 + row) * 16;
        *(uint4*)((char*)phi + off) = pack8(h);
        *(uint4*)((char*)plo + off) = pack8(l);
    }
    red[r][kq] = s;
    __syncthreads();
    if (tid < 16) {
        double t = 0.0;
#pragma unroll
        for (int q = 0; q < 16; ++q) t += red[tid][q];
        const int rw = blockIdx.x * 16 + tid;
        Lv[(rw % T_) * B_ + rw / T_] = (float)(t + cc[0]);
    }
}

// ---------------------------------------------------------------------------
// wepack: We -> packed planes  We'[by][kk][ko*128+n]
// ---------------------------------------------------------------------------
__global__ void wepack_kernel(const float* __restrict__ We,
                              u16* __restrict__ phi, u16* __restrict__ plo)
{
    const int kk = blockIdx.x, by = blockIdx.y, tid = threadIdx.x;
#pragma unroll
    for (int pass = 0; pass < 2; ++pass) {
        const int g = tid + pass * 256;
        const int ko = g >> 7, n = g & 127;
        const int p = by * 128 + n;
        const int k = kk * 32 + ko * 8;
        const float4 a = *(const float4*)&We[(size_t)p * FRAME_ + k];
        const float4 b = *(const float4*)&We[(size_t)p * FRAME_ + k + 4];
        const float f[8] = {a.x, a.y, a.z, a.w, b.x, b.y, b.z, b.w};
        u16 h[8], l[8];
#pragma unroll
        for (int e = 0; e < 8; ++e) {
            h[e] = f2bf_rn(f[e]);
            l[e] = f2bf_rn(f[e] - bf2f(h[e]));
        }
        const size_t off = (((size_t)by * 64 + kk) * 512 + g) * 16;
        *(uint4*)((char*)phi + off) = pack8(h);
        *(uint4*)((char*)plo + off) = pack8(l);
    }
}

// ---------------------------------------------------------------------------
// wihpack: W_ih (gate-interleaved n, K=512) -> Wih'[by][kk<16][g]
// whhpack: W_hh (gate-interleaved n, K=1024) -> Whh'[by][kk<32][g]
// ---------------------------------------------------------------------------
__global__ void wihpack_kernel(const float* __restrict__ Wih,
                               u16* __restrict__ phi, u16* __restrict__ plo)
{
    const int kk = blockIdx.x, by = blockIdx.y, tid = threadIdx.x;
#pragma unroll
    for (int pass = 0; pass < 2; ++pass) {
        const int g = tid + pass * 256;
        const int ko = g >> 7, n = g & 127;
        const int gate = n & 3, hl = n >> 2;
        const int srow = gate * HID_ + by * 32 + hl;
        const int k = kk * 32 + ko * 8;
        const float4 a = *(const float4*)&Wih[(size_t)srow * PROJ_ + k];
        const float4 b = *(const float4*)&Wih[(size_t)srow * PROJ_ + k + 4];
        const float f[8] = {a.x, a.y, a.z, a.w, b.x, b.y, b.z, b.w};
        u16 h[8], l[8];
#pragma unroll
        for (int e = 0; e < 8; ++e) {
            h[e] = f2bf_rn(f[e]);
            l[e] = f2bf_rn(f[e] - bf2f(h[e]));
        }
        const size_t off = (((size_t)by * 16 + kk) * 512 + g) * 16;
        *(uint4*)((char*)phi + off) = pack8(h);
        *(uint4*)((char*)plo + off) = pack8(l);
    }
}

__global__ void whhpack_kernel(const float* __restrict__ Whh,
                               u16* __restrict__ phi, u16* __restrict__ plo)
{
    const int kk = blockIdx.x, by = blockIdx.y, tid = threadIdx.x;
#pragma unroll
    for (int pass = 0; pass < 2; ++pass) {
        const int g = tid + pass * 256;
        const int ko = g >> 7, n = g & 127;
        const int gate = n & 3, hl = n >> 2;
        const int srow = gate * HID_ + by * 32 + hl;
        const int k = kk * 32 + ko * 8;
        const float4 a = *(const float4*)&Whh[(size_t)srow * HID_ + k];
        const float4 b = *(const float4*)&Whh[(size_t)srow * HID_ + k + 4];
        const float f[8] = {a.x, a.y, a.z, a.w, b.x, b.y, b.z, b.w};
        u16 h[8], l[8];
#pragma unroll
        for (int e = 0; e < 8; ++e) {
            h[e] = f2bf_rn(f[e]);
            l[e] = f2bf_rn(f[e] - bf2f(h[e]));
        }
        const size_t off = (((size_t)by * 32 + kk) * 512 + g) * 16;
        *(uint4*)((char*)phi + off) = pack8(h);
        *(uint4*)((char*)plo + off) = pack8(l);
    }
}

// b1g: gate-interleaved bias vector (added once into Gx)
__global__ void b1g_kernel(const float* __restrict__ bih, const float* __restrict__ bhh,
                           float* __restrict__ b1g)
{
    const int n = blockIdx.x * 256 + threadIdx.x;   // 4096
    const int by = n >> 7, nl = n & 127;
    const int gate = nl & 3, hl = nl >> 2;
    const int src = gate * HID_ + by * 32 + hl;
    b1g[n] = bih[src] + bhh[src];
}

// ---------------------------------------------------------------------------
// embed GEMM: vt = video @ We^T + be -> vt' packed planes.
// BM=64, BN=128, BK=32, 8 waves, 3-buf ONE-barrier pipeline, NK=64.
// Swizzle: each XCD owns a disjoint bx range; 4 by siblings adjacent.
// ---------------------------------------------------------------------------
__global__ __launch_bounds__(512, 1)
void embed_mfma_kernel(const u16* __restrict__ Ahi_g, const u16* __restrict__ Alo_g,
                       const u16* __restrict__ Bhi_g, const u16* __restrict__ Blo_g,
                       const float* __restrict__ be,
                       u16* __restrict__ vphi, u16* __restrict__ vplo)
{
    __shared__ char smem[73728];
    const int tid = threadIdx.x;
    const int xcd = blockIdx.x & 7, s_ = blockIdx.x >> 3;   // 1536 blocks
    const int by = s_ & 3, bx = xcd * 48 + (s_ >> 2);
    const int n0 = by * 128;
    const int w = tid >> 6, l = tid & 63, lm = l & 15, ko4 = l >> 4;
    const int wr = (w >> 2) * 32, wc = (w & 3) * 32;
    const int t8 = tid & 255;
    const int koA = t8 >> 6, am = t8 & 63;

    const char* aV = (const char*)(tid < 256 ? Ahi_g : Alo_g)
                     + (size_t)koA * 393216 + ((size_t)bx * 64 + am) * 16;
    const char* bh = (const char*)Bhi_g + (size_t)by * 524288 + tid * 16;
    const char* bl = (const char*)Blo_g + (size_t)by * 524288 + tid * 16;

    auto stage = [&](int s, int buf) {
        char* base = smem + buf * 24576;
        gld16(aV + (size_t)s * 1572864, base + (tid >> 8) * 4096 + t8 * 16);
        gld16(bh + (size_t)s * 8192, base + 8192 + tid * 16);
        gld16(bl + (size_t)s * 8192, base + 16384 + tid * 16);
    };

    f32x4 acc[2][2] = {};
    stage(0, 0);
    stage(1, 1);
    for (int kk = 0; kk < 64; ++kk) {
        if (kk < 63) asm volatile("s_waitcnt vmcnt(3)" ::: "memory");
        else         asm volatile("s_waitcnt vmcnt(0)" ::: "memory");
        __builtin_amdgcn_sched_barrier(0);
        __builtin_amdgcn_s_barrier();

        const char* rb = smem + (kk % 3) * 24576;
        bf16x8 fAh[2], fAl[2], fBh[2], fBl[2];
#pragma unroll
        for (int mt = 0; mt < 2; ++mt) {
            const int idx = ko4 * 64 + wr + mt * 16 + lm;
            fAh[mt] = *(const bf16x8*)(rb + idx * 16);
            fAl[mt] = *(const bf16x8*)(rb + 4096 + idx * 16);
        }
#pragma unroll
        for (int nt = 0; nt < 2; ++nt) {
            const int idx = ko4 * 128 + wc + nt * 16 + lm;
            fBh[nt] = *(const bf16x8*)(rb + 8192 + idx * 16);
            fBl[nt] = *(const bf16x8*)(rb + 16384 + idx * 16);
        }
        if (kk + 2 < 64) stage(kk + 2, (kk + 2) % 3);
        asm volatile("s_waitcnt lgkmcnt(0)" ::: "memory");
        __builtin_amdgcn_sched_barrier(0);
        __builtin_amdgcn_s_setprio(1);
#pragma unroll
        for (int mt = 0; mt < 2; ++mt)
#pragma unroll
            for (int nt = 0; nt < 2; ++nt) {
                acc[mt][nt] = __builtin_amdgcn_mfma_f32_16x16x32_bf16(fAh[mt], fBh[nt], acc[mt][nt], 0, 0, 0);
                acc[mt][nt] = __builtin_amdgcn_mfma_f32_16x16x32_bf16(fAh[mt], fBl[nt], acc[mt][nt], 0, 0, 0);
                acc[mt][nt] = __builtin_amdgcn_mfma_f32_16x16x32_bf16(fAl[mt], fBh[nt], acc[mt][nt], 0, 0, 0);
            }
        __builtin_amdgcn_s_setprio(0);
    }

    __syncthreads();
    float* S = (float*)smem;   // [64][132]
#pragma unroll
    for (int mt = 0; mt < 2; ++mt)
#pragma unroll
        for (int nt = 0; nt < 2; ++nt) {
            const int col = wc + nt * 16 + lm;
#pragma unroll
            for (int r = 0; r < 4; ++r) {
                const int row = wr + mt * 16 + ko4 * 4 + r;
                S[row * 132 + col] = acc[mt][nt][r];
            }
        }
    __syncthreads();

#pragma unroll
    for (int pass = 0; pass < 2; ++pass) {
        const int pidx = tid + pass * 512;
        const int m = pidx >> 4, gr = pidx & 15;
        const int p0 = n0 + gr * 8;
        const float4 s0 = *(const float4*)&S[m * 132 + gr * 8];
        const float4 s1 = *(const float4*)&S[m * 132 + gr * 8 + 4];
        const float4 e0 = *(const float4*)&be[p0];
        const float4 e1 = *(const float4*)&be[p0 + 4];
        const float o[8] = {s0.x + e0.x, s0.y + e0.y, s0.z + e0.z, s0.w + e0.w,
                            s1.x + e1.x, s1.y + e1.y, s1.z + e1.z, s1.w + e1.w};
        u16 h[8], lo[8];
#pragma unroll
        for (int e = 0; e < 8; ++e) {
            h[e] = f2bf_rn(o[e]);
            lo[e] = f2bf_rn(o[e] - bf2f(h[e]));
        }
        const int R = bx * 64 + m;
        const int t = R % T_, b = R / T_;
        const size_t off = (size_t)t * 524288 + (((size_t)(p0 >> 3)) * 512 + b) * 16;
        *(uint4*)((char*)vphi + off) = pack8(h);
        *(uint4*)((char*)vplo + off) = pack8(lo);
    }
}

// ---------------------------------------------------------------------------
// gx GEMM: Gx[t*B+b][n'] = vt' @ Wih'^T + b1g   (fp32, gate-interleaved n')
// grid 12288 = (48 t x 8 bx) x 32 by; BM=64, BN=128, NK=16, one-barrier.
// ---------------------------------------------------------------------------
__global__ __launch_bounds__(512, 1)
void gx_mfma_kernel(const u16* __restrict__ vphi, const u16* __restrict__ vplo,
                    const u16* __restrict__ Wihhi, const u16* __restrict__ Wihlo,
                    const float* __restrict__ b1g, float* __restrict__ Gx)
{
    __shared__ char smem[73728];
    const int tid = threadIdx.x;
    const int by = blockIdx.x & 31;
    const int tb = blockIdx.x >> 5;          // 0..383
    const int t = tb >> 3, bx = tb & 7;
    const int b0 = bx * 64, n0 = by * 128;
    const int w = tid >> 6, l = tid & 63, lm = l & 15, ko4 = l >> 4;
    const int wr = (w >> 2) * 32, wc = (w & 3) * 32;
    const int t8 = tid & 255;
    const int koA = t8 >> 6, am = t8 & 63;

    const char* aV = (const char*)(tid < 256 ? vphi : vplo)
                     + (size_t)t * 524288 + ((size_t)koA * 512 + b0 + am) * 16;
    const char* bh = (const char*)Wihhi + (size_t)by * 131072 + tid * 16;
    const char* bl = (const char*)Wihlo + (size_t)by * 131072 + tid * 16;

    auto stage = [&](int s, int buf) {
        char* base = smem + buf * 24576;
        gld16(aV + s * 32768, base + (tid >> 8) * 4096 + t8 * 16);
        gld16(bh + s * 8192, base + 8192 + tid * 16);
        gld16(bl + s * 8192, base + 16384 + tid * 16);
    };

    f32x4 acc[2][2] = {};
    stage(0, 0);
    stage(1, 1);
    for (int kk = 0; kk < 16; ++kk) {
        if (kk < 15) asm volatile("s_waitcnt vmcnt(3)" ::: "memory");
        else         asm volatile("s_waitcnt vmcnt(0)" ::: "memory");
        __builtin_amdgcn_sched_barrier(0);
        __builtin_amdgcn_s_barrier();

        const char* rb = smem + (kk % 3) * 24576;
        bf16x8 fAh[2], fAl[2], fBh[2], fBl[2];
#pragma unroll
        for (int mt = 0; mt < 2; ++mt) {
            const int idx = ko4 * 64 + wr + mt * 16 + lm;
            fAh[mt] = *(const bf16x8*)(rb + idx * 16);
            fAl[mt] = *(const bf16x8*)(rb + 4096 + idx * 16);
        }
#pragma unroll
        for (int nt = 0; nt < 2; ++nt) {
            const int idx = ko4 * 128 + wc + nt * 16 + lm;
            fBh[nt] = *(const bf16x8*)(rb + 8192 + idx * 16);
            fBl[nt] = *(const bf16x8*)(rb + 16384 + idx * 16);
        }
        if (kk + 2 < 16) stage(kk + 2, (kk + 2) % 3);
        asm volatile("s_waitcnt lgkmcnt(0)" ::: "memory");
        __builtin_amdgcn_sched_barrier(0);
        __builtin_amdgcn_s_setprio(1);
#pragma unroll
        for (int mt = 0; mt < 2; ++mt)
#pragma unroll
            for (int nt = 0; nt < 2; ++nt) {
                acc[mt][nt] = __builtin_amdgcn_mfma_f32_16x16x32_bf16(fAh[mt], fBh[nt], acc[mt][nt], 0, 0, 0);
                acc[mt][nt] = __builtin_amdgcn_mfma_f32_16x16x32_bf16(fAh[mt], fBl[nt], acc[mt][nt], 0, 0, 0);
                acc[mt][nt] = __builtin_amdgcn_mfma_f32_16x16x32_bf16(fAl[mt], fBh[nt], acc[mt][nt], 0, 0, 0);
            }
        __builtin_amdgcn_s_setprio(0);
    }

    __syncthreads();
    float* S = (float*)smem;   // [64][132]
#pragma unroll
    for (int mt = 0; mt < 2; ++mt)
#pragma unroll
        for (int nt = 0; nt < 2; ++nt) {
            const int col = wc + nt * 16 + lm;
#pragma unroll
            for (int r = 0; r < 4; ++r) {
                const int row = wr + mt * 16 + ko4 * 4 + r;
                S[row * 132 + col] = acc[mt][nt][r];
            }
        }
    __syncthreads();

#pragma unroll
    for (int pass = 0; pass < 2; ++pass) {
        const int pidx = tid + pass * 512;
        const int m = pidx >> 4, gr = pidx & 15;
        const int c0 = gr * 8;
        const float4 s0 = *(const float4*)&S[m * 132 + c0];
        const float4 s1 = *(const float4*)&S[m * 132 + c0 + 4];
        const float4 a0 = *(const float4*)&b1g[n0 + c0];
        const float4 a1 = *(const float4*)&b1g[n0 + c0 + 4];
        float* dst = Gx + ((size_t)t * 512 + b0 + m) * 4096 + n0 + c0;
        *(float4*)dst       = make_float4(s0.x + a0.x, s0.y + a0.y, s0.z + a0.z, s0.w + a0.w);
        *(float4*)(dst + 4) = make_float4(s1.x + a1.x, s1.y + a1.y, s1.z + a1.z, s1.w + a1.w);
    }
}

// ---------------------------------------------------------------------------
// LSTM1 step: gates = Gx[t] + h @ Whh'^T ; K=1024 (NK=32), one-barrier.
// Fused keep + cell update + Pout partials + packed h' output.
// ---------------------------------------------------------------------------
__global__ __launch_bounds__(512, 1)
void lstm_mfma_kernel(const u16* __restrict__ hhi,  const u16* __restrict__ hlo,
                      const u16* __restrict__ Whhhi, const u16* __restrict__ Whhlo,
                      const float* __restrict__ Gxt,
                      const float* __restrict__ Lv_t,
                      const float* __restrict__ Pin,
                      float* __restrict__ Pout,
                      const float* __restrict__ wsh_v,
                      float* __restrict__ c1, float* __restrict__ h1o,
                      u16* __restrict__ hhio, u16* __restrict__ hloo)
{
    __shared__ char smem[73984];
    float* keepsm = (float*)(smem + 73728);
    const int tid = threadIdx.x;
    const int bid = blockIdx.x;
    const int xcd = bid & 7, slot = bid >> 3;
    const int by  = xcd * 4 + (slot & 3);
    const int bx  = slot >> 2;
    const int b0  = bx * 64;
    const int w = tid >> 6, l = tid & 63, lm = l & 15, ko4 = l >> 4;
    const int wr = (w >> 2) * 32, wc = (w & 3) * 32;
    const int t8 = tid & 255;
    const int koA = t8 >> 6, am = t8 & 63;

    const char* aH = (const char*)(tid < 256 ? hhi : hlo)
                     + ((size_t)koA * 512 + b0 + am) * 16;
    const char* bh = (const char*)Whhhi + (size_t)by * 262144 + tid * 16;
    const char* bl = (const char*)Whhlo + (size_t)by * 262144 + tid * 16;

    auto stage = [&](int s, int buf) {
        char* base = smem + buf * 24576;
        gld16(aH + s * 32768, base + (tid >> 8) * 4096 + t8 * 16);
        gld16(bh + s * 8192, base + 8192 + tid * 16);
        gld16(bl + s * 8192, base + 16384 + tid * 16);
    };

    f32x4 acc[2][2] = {};
    stage(0, 0);
    stage(1, 1);

    if (tid < 64) {
        double s = (double)Lv_t[b0 + tid];
#pragma unroll
        for (int j = 0; j < 32; ++j) s += (double)Pin[j * B_ + b0 + tid];
        keepsm[tid] = (s > 0.0) ? 0.0f : 1.0f;
    }

    for (int kk = 0; kk < 32; ++kk) {
        if (kk < 31) asm volatile("s_waitcnt vmcnt(3)" ::: "memory");
        else         asm volatile("s_waitcnt vmcnt(0)" ::: "memory");
        __builtin_amdgcn_sched_barrier(0);
        __builtin_amdgcn_s_barrier();

        const char* rb = smem + (kk % 3) * 24576;
        bf16x8 fAh[2], fAl[2], fBh[2], fBl[2];
#pragma unroll
        for (int mt = 0; mt < 2; ++mt) {
            const int idx = ko4 * 64 + wr + mt * 16 + lm;
            fAh[mt] = *(const bf16x8*)(rb + idx * 16);
            fAl[mt] = *(const bf16x8*)(rb + 4096 + idx * 16);
        }
#pragma unroll
        for (int nt = 0; nt < 2; ++nt) {
            const int idx = ko4 * 128 + wc + nt * 16 + lm;
            fBh[nt] = *(const bf16x8*)(rb + 8192 + idx * 16);
            fBl[nt] = *(const bf16x8*)(rb + 16384 + idx * 16);
        }
        if (kk + 2 < 32) stage(kk + 2, (kk + 2) % 3);
        asm volatile("s_waitcnt lgkmcnt(0)" ::: "memory");
        __builtin_amdgcn_sched_barrier(0);
        __builtin_amdgcn_s_setprio(1);
#pragma unroll
        for (int mt = 0; mt < 2; ++mt)
#pragma unroll
            for (int nt = 0; nt < 2; ++nt) {
                acc[mt][nt] = __builtin_amdgcn_mfma_f32_16x16x32_bf16(fAh[mt], fBh[nt], acc[mt][nt], 0, 0, 0);
                acc[mt][nt] = __builtin_amdgcn_mfma_f32_16x16x32_bf16(fAh[mt], fBl[nt], acc[mt][nt], 0, 0, 0);
                acc[mt][nt] = __builtin_amdgcn_mfma_f32_16x16x32_bf16(fAl[mt], fBh[nt], acc[mt][nt], 0, 0, 0);
            }
        __builtin_amdgcn_s_setprio(0);
    }

    // prefetch Gx quadrant (addresses independent of S-exchange)
    const int h_l = tid & 31, rg = tid >> 5;
    const int hg  = by * 32 + h_l;
    float4 gx[4];
#pragma unroll
    for (int i = 0; i < 4; ++i)
        gx[i] = *(const float4*)&Gxt[((size_t)b0 + rg * 4 + i) * 4096 + by * 128 + h_l * 4];

    __syncthreads();
    float* S = (float*)smem;   // [64][132]
#pragma unroll
    for (int mt = 0; mt < 2; ++mt)
#pragma unroll
        for (int nt = 0; nt < 2; ++nt) {
            const int col = wc + nt * 16 + lm;
#pragma unroll
            for (int r = 0; r < 4; ++r) {
                const int row = wr + mt * 16 + ko4 * 4 + r;
                S[row * 132 + col] = acc[mt][nt][r];
            }
        }
    __syncthreads();

    const float wv = wsh_v[hg];
    const size_t hgbase = (((size_t)by * 4 + (h_l >> 3)) * 512) * 16 + (h_l & 7) * 2;
#pragma unroll
    for (int i = 0; i < 4; ++i) {
        const int m = rg * 4 + i;
        const int b = b0 + m;
        const float4 g4 = *(const float4*)&S[m * 132 + h_l * 4];
        const float i_ = sigmoidf_(g4.x + gx[i].x);
        const float f_ = sigmoidf_(g4.y + gx[i].y);
        const float g_ = tanhf(g4.z + gx[i].z);
        const float o_ = sigmoidf_(g4.w + gx[i].w);
        const size_t off = (size_t)b * HID_ + hg;
        float cn = f_ * c1[off] + i_ * g_;
        float hn = o_ * tanhf(cn);
        const float kp = keepsm[m];
        cn *= kp; hn *= kp;
        c1[off] = cn;
        if (h1o) h1o[off] = hn;
        const u16 hb = f2bf_rn(hn);
        const size_t hoff = hgbase + (size_t)b * 16;
        *(u16*)((char*)hhio + hoff) = hb;
        *(u16*)((char*)hloo + hoff) = f2bf_rn(hn - bf2f(hb));
        float pr = hn * wv;
        pr += __shfl_xor(pr, 16);
        pr += __shfl_xor(pr, 8);
        pr += __shfl_xor(pr, 4);
        pr += __shfl_xor(pr, 2);
        pr += __shfl_xor(pr, 1);
        if (h_l == 0) Pout[by * B_ + b] = pr;
    }
}

// ---------------------------------------------------------------------------
extern "C" void kernel_launch(void* const* d_in, const int* in_sizes, int n_in,
                              void* d_out, int out_size, void* d_ws, size_t ws_size,
                              hipStream_t stream)
{
    const float* video = (const float*)d_in[0];
    const float* We    = (const float*)d_in[1];
    const float* be    = (const float*)d_in[2];
    const float* W1_ih = (const float*)d_in[3];
    const float* W1_hh = (const float*)d_in[4];
    const float* b1_ih = (const float*)d_in[5];
    const float* b1_hh = (const float*)d_in[6];
    // d_in[7], d_in[8] (W2_ih, W2_hh): dead — lstm2 never affects the output
    const float* Wsi   = (const float*)d_in[9];
    const float* Wsh   = (const float*)d_in[10];
    const float* bbd   = (const float*)d_in[11];
    const float* vs    = (const float*)d_in[12];
    float* out = (float*)d_out;

    char* p = (char*)d_ws;
    auto alloc = [&](size_t bytes) { char* r = p; p += (bytes + 255) & ~(size_t)255; return r; };
    u16* vidhi = (u16*)alloc((size_t)24576 * FRAME_ * 2);   // 96 MB
    u16* vidlo = (u16*)alloc((size_t)24576 * FRAME_ * 2);   // 96 MB
    u16* vphi  = (u16*)alloc((size_t)T_ * B_ * PROJ_ * 2);  // 24 MB
    u16* vplo  = (u16*)alloc((size_t)T_ * B_ * PROJ_ * 2);
    u16* Wehi  = (u16*)alloc((size_t)PROJ_ * FRAME_ * 2);
    u16* Welo  = (u16*)alloc((size_t)PROJ_ * FRAME_ * 2);
    u16* Wihhi = (u16*)alloc((size_t)G4_ * PROJ_ * 2);      // 4 MB
    u16* Wihlo = (u16*)alloc((size_t)G4_ * PROJ_ * 2);
    u16* Whhhi = (u16*)alloc((size_t)G4_ * HID_ * 2);       // 8 MB
    u16* Whhlo = (u16*)alloc((size_t)G4_ * HID_ * 2);
    float* Gx  = (float*)alloc((size_t)T_ * B_ * G4_ * 4);  // 402.7 MB
    float* c1  = (float*)alloc((size_t)B_ * HID_ * 4);
    u16* hhiA  = (u16*)alloc((size_t)B_ * HID_ * 2);
    u16* hhiB  = (u16*)alloc((size_t)B_ * HID_ * 2);
    u16* hloA  = (u16*)alloc((size_t)B_ * HID_ * 2);
    u16* hloB  = (u16*)alloc((size_t)B_ * HID_ * 2);
    double* wsi_vd = (double*)alloc(512 * 8);
    double* ud     = (double*)alloc(2048 * 8);
    double* ccd    = (double*)alloc(256);
    float* wsh_v = (float*)alloc(1024 * 4);
    float* Lv    = (float*)alloc((size_t)T_ * B_ * 4);
    float* PA    = (float*)alloc(32 * B_ * 4);
    float* PB    = (float*)alloc(32 * B_ * 4);
    float* b1g   = (float*)alloc(G4_ * 4);

    hipMemsetAsync(c1,   0, (size_t)B_ * HID_ * 4, stream);
    hipMemsetAsync(hhiA, 0, (size_t)B_ * HID_ * 2, stream);
    hipMemsetAsync(hloA, 0, (size_t)B_ * HID_ * 2, stream);
    hipMemsetAsync(PA,   0, 32 * B_ * 4, stream);

    b1g_kernel<<<16, 256, 0, stream>>>(b1_ih, b1_hh, b1g);
    wvec_kernel<<<6, 256, 0, stream>>>(Wsi, Wsh, vs, wsi_vd, wsh_v);
    cc_kernel<<<1, 256, 0, stream>>>(be, wsi_vd, vs, bbd, ccd);
    u_kernel<<<8, 256, 0, stream>>>(We, wsi_vd, ud);
    wepack_kernel<<<dim3(64, 4), 256, 0, stream>>>(We, Wehi, Welo);
    wihpack_kernel<<<dim3(16, 32), 256, 0, stream>>>(W1_ih, Wihhi, Wihlo);
    whhpack_kernel<<<dim3(32, 32), 256, 0, stream>>>(W1_hh, Whhhi, Whhlo);
    vidpack_kernel<<<1536, 256, 0, stream>>>(video, ud, ccd, vidhi, vidlo, Lv);
    embed_mfma_kernel<<<1536, 512, 0, stream>>>(vidhi, vidlo, Wehi, Welo, be, vphi, vplo);
    gx_mfma_kernel<<<12288, 512, 0, stream>>>(vphi, vplo, Wihhi, Wihlo, b1g, Gx);

    u16* hhi_in = hhiA; u16* hhi_out = hhiB;
    u16* hlo_in = hloA; u16* hlo_out = hloB;
    float* Pin = PA; float* Pout = PB;

    for (int t = 0; t < T_; ++t) {
        float* ho = (t == T_ - 1) ? out : nullptr;
        lstm_mfma_kernel<<<256, 512, 0, stream>>>(hhi_in, hlo_in, Whhhi, Whhlo,
                                                  Gx + (size_t)t * B_ * G4_,
                                                  Lv + t * B_, Pin, Pout, wsh_v,
                                                  c1, ho, hhi_out, hlo_out);
        { u16* tmp = hhi_in; hhi_in = hhi_out; hhi_out = tmp; }
        { u16* tmp = hlo_in; hlo_in = hlo_out; hlo_out = tmp; }
        { float* tmp = Pin; Pin = Pout; Pout = tmp; }
    }
}